// Round 1
// baseline (1256.845 us; speedup 1.0000x reference)
//
#include <hip/hip_runtime.h>

// Shapes (fixed by the problem)
#define B_  16
#define N_  1000
#define NP  1024      // padded N for bf16 GEMM operands
#define DN  64
#define D_  128

typedef __attribute__((ext_vector_type(8))) short  short8;
typedef __attribute__((ext_vector_type(4))) float  f32x4;

// ---------------- helpers ----------------
__device__ __forceinline__ unsigned short f2bf(float v) {
  union { float f; unsigned int u; } c; c.f = v;
  unsigned int u = c.u;
  unsigned int r = (u + 0x7fffu + ((u >> 16) & 1u)) >> 16;   // RNE
  return (unsigned short)r;
}
__device__ __forceinline__ float bf2f(unsigned short h) {
  union { unsigned int u; float f; } c; c.u = ((unsigned int)h) << 16; return c.f;
}

__device__ __forceinline__ float wred_sum(float v) {
  #pragma unroll
  for (int o = 32; o > 0; o >>= 1) v += __shfl_down(v, o);
  return v;
}

// block-wide reductions; all callers use blockDim.x == 256 (4 waves)
__device__ __forceinline__ void block_red2(float& a, float& b) {
  __shared__ float sb[8];
  __syncthreads();
  float ra = a, rb = b;
  #pragma unroll
  for (int o = 32; o > 0; o >>= 1) { ra += __shfl_down(ra, o); rb += __shfl_down(rb, o); }
  int w = threadIdx.x >> 6;
  if ((threadIdx.x & 63) == 0) { sb[w] = ra; sb[4 + w] = rb; }
  __syncthreads();
  a = sb[0] + sb[1] + sb[2] + sb[3];
  b = sb[4] + sb[5] + sb[6] + sb[7];
}

__device__ __forceinline__ void block_redmax(float& a) {
  __shared__ float sm[4];
  __syncthreads();
  float ra = a;
  #pragma unroll
  for (int o = 32; o > 0; o >>= 1) ra = fmaxf(ra, __shfl_down(ra, o));
  if ((threadIdx.x & 63) == 0) sm[threadIdx.x >> 6] = ra;
  __syncthreads();
  a = fmaxf(fmaxf(sm[0], sm[1]), fmaxf(sm[2], sm[3]));
}

// ---------------- tiny setup: w_eff, zero tr/fnorm ----------------
__global__ void prep_kernel(const float* __restrict__ mlp_w, const float* __restrict__ mlp_b,
                            float* __restrict__ weff, float* __restrict__ tr, float* __restrict__ fnorm) {
  int t = threadIdx.x;
  if (t < 8) {
    float s = 1.f;                    // +1 from the residual branch of the 1x1 conv
    for (int o = 0; o < 8; ++o) s += mlp_w[o * 8 + t];
    weff[t] = s;
  }
  if (t < 16) tr[t] = 0.f;
  if (t == 16) fnorm[0] = 0.f;
  (void)mlp_b;  // b_eff is added uniformly pre-LayerNorm -> shift-invariant -> no-op
}

// ---------------- transpose + cast + zero-pad: [1000x1000]f32 -> [1024x1024]bf16^T ----------------
__global__ void transpose_pad(const float* __restrict__ in, unsigned short* __restrict__ out) {
  __shared__ float tile[32][33];
  int bx = blockIdx.x * 32, by = blockIdx.y * 32;
  int tx = threadIdx.x, ty = threadIdx.y;      // (32,8)
  #pragma unroll
  for (int i = 0; i < 32; i += 8) {
    int r = by + ty + i, c = bx + tx;
    tile[ty + i][tx] = (r < N_ && c < N_) ? in[(long)r * N_ + c] : 0.f;
  }
  __syncthreads();
  #pragma unroll
  for (int i = 0; i < 32; i += 8) {
    int r = bx + ty + i, c = by + tx;          // out[r][c] = in[c][r]
    out[(long)r * NP + c] = f2bf(tile[tx][ty + i]);
  }
}

// ---------------- small gram: C[i,j] = X[i,:]·X[j,:], X [1000x64] ----------------
__global__ void gram_kernel(const float* __restrict__ X, float* __restrict__ C) {
  __shared__ float Xi[16][65], Xj[16][65];
  int tx = threadIdx.x, ty = threadIdx.y;      // (16,16)
  int i0 = blockIdx.y * 16, j0 = blockIdx.x * 16;
  #pragma unroll
  for (int kk = 0; kk < 64; kk += 16) {
    int r = i0 + ty;  Xi[ty][kk + tx] = (r < N_) ? X[(long)r * DN + kk + tx] : 0.f;
    int rj = j0 + ty; Xj[ty][kk + tx] = (rj < N_) ? X[(long)rj * DN + kk + tx] : 0.f;
  }
  __syncthreads();
  float acc = 0.f;
  #pragma unroll
  for (int d = 0; d < 64; ++d) acc += Xi[ty][d] * Xj[tx][d];
  int i = i0 + ty, j = j0 + tx;
  if (i < N_ && j < N_) C[(long)i * N_ + j] = acc;
}

// ---------------- row LayerNorm (in place), rows of length 1000 ----------------
__global__ void row_ln(float* __restrict__ base, long bstride) {
  int tid = threadIdx.x;
  float* row = base + (long)blockIdx.y * bstride + (long)blockIdx.x * N_;
  float x[4]; float s = 0.f, s2 = 0.f;
  #pragma unroll
  for (int i = 0; i < 4; ++i) {
    int idx = tid + i * 256;
    x[i] = (idx < N_) ? row[idx] : 0.f;
    s += x[i]; s2 += x[i] * x[i];
  }
  block_red2(s, s2);
  float mean = s * 1e-3f, var = s2 * 1e-3f - mean * mean;
  float r = rsqrtf(var + 1e-5f);
  #pragma unroll
  for (int i = 0; i < 4; ++i) {
    int idx = tid + i * 256;
    if (idx < N_) row[idx] = (x[i] - mean) * r;
  }
}

// ---------------- row LN -> relu -> softmax (adj_static), plus rowsum ----------------
__global__ void row_ln_sm(float* __restrict__ mat, float* __restrict__ rowsum) {
  int n = blockIdx.x, tid = threadIdx.x;
  float* row = mat + (long)n * N_;
  float x[4]; float s = 0.f, s2 = 0.f;
  #pragma unroll
  for (int i = 0; i < 4; ++i) {
    int idx = tid + i * 256;
    x[i] = (idx < N_) ? row[idx] : 0.f;
    s += x[i]; s2 += x[i] * x[i];
  }
  block_red2(s, s2);
  float mean = s * 1e-3f, var = s2 * 1e-3f - mean * mean;
  float r = rsqrtf(var + 1e-5f);
  float mx = -1e30f;
  #pragma unroll
  for (int i = 0; i < 4; ++i) {
    int idx = tid + i * 256;
    if (idx < N_) { x[i] = fmaxf((x[i] - mean) * r, 0.f); mx = fmaxf(mx, x[i]); }
  }
  block_redmax(mx);
  float es = 0.f, d = 0.f;
  #pragma unroll
  for (int i = 0; i < 4; ++i) {
    int idx = tid + i * 256;
    if (idx < N_) { x[i] = __expf(x[i] - mx); es += x[i]; } else x[i] = 0.f;
  }
  block_red2(es, d);
  float inv = 1.f / es; float ps = 0.f;
  #pragma unroll
  for (int i = 0; i < 4; ++i) {
    int idx = tid + i * 256;
    if (idx < N_) { x[i] *= inv; row[idx] = x[i]; ps += x[i]; }
  }
  d = 0.f; block_red2(ps, d);
  if (tid == 0) rowsum[n] = ps;
}

// ---------------- fusion LN + nv11 + q/k (leaky, w_eff/4 folded into q) + sq ----------------
__global__ __launch_bounds__(128)
void fusion_qk(const float* __restrict__ fus, const float* __restrict__ node_w,
               const float* __restrict__ w_q, const float* __restrict__ w_k,
               const float* __restrict__ weff, const float* __restrict__ node_input,
               unsigned short* __restrict__ nv11, unsigned short* __restrict__ qs,
               unsigned short* __restrict__ kb, float* __restrict__ sq) {
  __shared__ float wq_s[DN * D_];
  __shared__ float wk_s[DN * D_];
  __shared__ float f_s[DN];
  __shared__ float red_s[2];
  int tid = threadIdx.x;
  for (int i = tid; i < DN * D_; i += 128) { wq_s[i] = w_q[i]; wk_s[i] = w_k[i]; }
  float we = weff[tid >> 4] * 0.25f;   // per-head scale / sqrt(hd)
  __syncthreads();
  for (int r = 0; r < 16; ++r) {
    int row_id = blockIdx.x * 16 + r;           // 0..15999
    int b = row_id / N_, n = row_id % N_;
    if (tid < 64) {
      float xv = fus[(long)row_id * DN + tid];
      float s = xv, s2 = xv * xv;
      #pragma unroll
      for (int o = 32; o > 0; o >>= 1) { s += __shfl_down(s, o); s2 += __shfl_down(s2, o); }
      s = __shfl(s, 0); s2 = __shfl(s2, 0);
      float mean = s * (1.f / DN);
      float var  = s2 * (1.f / DN) - mean * mean;
      float rln  = rsqrtf(var + 1e-5f);
      float fv = (xv - mean) * rln;
      f_s[tid] = fv;
      float rs = fv;
      #pragma unroll
      for (int o = 32; o > 0; o >>= 1) rs += __shfl_down(rs, o);
      if (tid == 0) red_s[0] = rs;
      float xi = node_input[(long)row_id * DN + tid];
      float q2 = xi * xi;
      #pragma unroll
      for (int o = 32; o > 0; o >>= 1) q2 += __shfl_down(q2, o);
      if (tid == 0) sq[row_id] = q2;
    }
    __syncthreads();
    if (tid < 64) {
      float v = red_s[0] * node_w[(long)n * DN + tid] + f_s[tid];
      nv11[((long)b * NP + n) * DN + tid] = f2bf(v);
    }
    float aq = 0.f, ak = 0.f;
    #pragma unroll 8
    for (int d = 0; d < DN; ++d) {
      float fv = f_s[d];
      aq += fv * wq_s[d * D_ + tid];
      ak += fv * wk_s[d * D_ + tid];
    }
    aq = (aq > 0.f) ? aq : 0.01f * aq;    // leaky_relu
    ak = (ak > 0.f) ? ak : 0.01f * ak;
    qs[((long)b * NP + n) * D_ + tid] = f2bf(aq * we);
    kb[((long)b * NP + n) * D_ + tid] = f2bf(ak);
    __syncthreads();
  }
}

// ---------------- batched bf16 MFMA GEMM: C[b] = X[b] · Y[b]^T (m97-style 128^2 tile) ----------------
#define GLOAD_LDS16(gp, lp) \
  __builtin_amdgcn_global_load_lds((const __attribute__((address_space(1))) void*)(gp), \
                                   (__attribute__((address_space(3))) void*)(lp), 16, 0, 0)

// EPI 0: bounds-checked f32 store, stride 1000.  EPI 1: relu -> bf16 full-tile store, stride 1024.
template<int EPI>
__global__ __launch_bounds__(256, 2)
void gemm_bt(const unsigned short* __restrict__ X, long xbs, int ldx,
             const unsigned short* __restrict__ Y, long ybs, int ldy,
             int K,
             float* __restrict__ outF, long obsF,
             unsigned short* __restrict__ outB, long obsB) {
  __shared__ __align__(16) short As[128 * 32];
  __shared__ __align__(16) short Bs[128 * 32];
  const int tid = threadIdx.x;
  const int b  = blockIdx.z;
  const int m0 = blockIdx.x * 128;
  const int n0 = blockIdx.y * 128;
  const unsigned short* Xb = X + (long)b * xbs + (long)m0 * ldx;
  const unsigned short* Yb = Y + (long)b * ybs + (long)n0 * ldy;

  const int lane = tid & 63, w = tid >> 6;
  const int wm = (w >> 1) * 64, wn = (w & 1) * 64;   // 2x2 waves -> 64x64 each
  const int fr = lane & 15, kg = lane >> 4;

  // staging map: thread -> (row sr, k-slot ks); source column XOR-swizzled so that
  // LDS[row][slot] = X[row][(slot ^ p_row)*8 ..], p_row = (row>>1)&3  (rule 21: same involution on read)
  const int sr = tid >> 2;
  const int ks = tid & 3;
  const int c1 = ((ks ^ ((sr >> 1) & 3)) * 8);
  const int c2 = ((ks ^ (((sr + 64) >> 1) & 3)) * 8);

  f32x4 acc[4][4];
  #pragma unroll
  for (int mi = 0; mi < 4; ++mi)
    #pragma unroll
    for (int ni = 0; ni < 4; ++ni)
      acc[mi][ni] = (f32x4){0.f, 0.f, 0.f, 0.f};

  const short* Asp = (const short*)As;
  const short* Bsp = (const short*)Bs;

  for (int k0 = 0; k0 < K; k0 += 32) {
    GLOAD_LDS16(Xb + (long)sr * ldx + k0 + c1,        (char*)As + tid * 16);
    GLOAD_LDS16(Xb + (long)(sr + 64) * ldx + k0 + c2, (char*)As + 4096 + tid * 16);
    GLOAD_LDS16(Yb + (long)sr * ldy + k0 + c1,        (char*)Bs + tid * 16);
    GLOAD_LDS16(Yb + (long)(sr + 64) * ldy + k0 + c2, (char*)Bs + 4096 + tid * 16);
    __syncthreads();   // compiler emits s_waitcnt vmcnt(0) before s_barrier -> LDS valid
    short8 av[4], bv[4];
    #pragma unroll
    for (int mi = 0; mi < 4; ++mi) {
      int r = wm + mi * 16 + fr;
      av[mi] = *(const short8*)&Asp[r * 32 + ((kg ^ ((r >> 1) & 3)) * 8)];
    }
    #pragma unroll
    for (int ni = 0; ni < 4; ++ni) {
      int r = wn + ni * 16 + fr;
      bv[ni] = *(const short8*)&Bsp[r * 32 + ((kg ^ ((r >> 1) & 3)) * 8)];
    }
    #pragma unroll
    for (int mi = 0; mi < 4; ++mi)
      #pragma unroll
      for (int ni = 0; ni < 4; ++ni)
        acc[mi][ni] = __builtin_amdgcn_mfma_f32_16x16x32_bf16(av[mi], bv[ni], acc[mi][ni], 0, 0, 0);
    __syncthreads();   // protect LDS from next-iter staging
  }

  // C/D layout (m89-verified): col = lane&15, row = (lane>>4)*4 + reg
  if (EPI == 0) {
    float* ob = outF + (long)b * obsF;
    #pragma unroll
    for (int mi = 0; mi < 4; ++mi) {
      #pragma unroll
      for (int ni = 0; ni < 4; ++ni) {
        int col  = n0 + wn + ni * 16 + fr;
        int rowb = m0 + wm + mi * 16 + kg * 4;
        #pragma unroll
        for (int j = 0; j < 4; ++j) {
          int row = rowb + j;
          if (row < N_ && col < N_) ob[(long)row * N_ + col] = acc[mi][ni][j];
        }
      }
    }
  } else {
    unsigned short* ob = outB + (long)b * obsB;
    #pragma unroll
    for (int mi = 0; mi < 4; ++mi) {
      #pragma unroll
      for (int ni = 0; ni < 4; ++ni) {
        int col  = n0 + wn + ni * 16 + fr;
        int rowb = m0 + wm + mi * 16 + kg * 4;
        #pragma unroll
        for (int j = 0; j < 4; ++j) {
          int row = rowb + j;
          ob[(long)row * NP + col] = f2bf(fmaxf(acc[mi][ni][j], 0.f));
        }
      }
    }
  }
}

// ---------------- adj_bf = ln(A_pre)+skip (in place), t = bf16(ln(adj_bf)) zero-padded ----------------
__global__ void row_combine1(float* __restrict__ apre, const float* __restrict__ skip,
                             unsigned short* __restrict__ t) {
  int n = blockIdx.x, b = blockIdx.y, tid = threadIdx.x;
  long ro = (long)b * 1000000 + (long)n * N_;
  float* arow = apre + ro;
  const float* srow = skip + ro;
  float x[4]; float s = 0.f, s2 = 0.f;
  #pragma unroll
  for (int i = 0; i < 4; ++i) {
    int idx = tid + i * 256;
    x[i] = (idx < N_) ? arow[idx] : 0.f;
    s += x[i]; s2 += x[i] * x[i];
  }
  block_red2(s, s2);
  float mean = s * 1e-3f, var = s2 * 1e-3f - mean * mean;
  float r = rsqrtf(var + 1e-5f);
  float y[4]; s = 0.f; s2 = 0.f;
  #pragma unroll
  for (int i = 0; i < 4; ++i) {
    int idx = tid + i * 256;
    if (idx < N_) { y[i] = (x[i] - mean) * r + srow[idx]; arow[idx] = y[i]; }
    else y[i] = 0.f;
    s += y[i]; s2 += y[i] * y[i];
  }
  block_red2(s, s2);
  float mean2 = s * 1e-3f, var2 = s2 * 1e-3f - mean2 * mean2;
  float r2 = rsqrtf(var2 + 1e-5f);
  unsigned short* trow = t + ((long)b * NP + n) * NP;
  #pragma unroll
  for (int i = 0; i < 4; ++i) {
    int idx = tid + i * 256;                     // covers 0..1023
    float v = (idx < N_) ? (y[i] - mean2) * r2 : 0.f;
    trow[idx] = f2bf(v);
  }
}

// ---------------- final chain: ln(G2+adj_bf); +sgi; ln; relu; softmax -> in place on region0 ----------------
__global__ void row_final(float* __restrict__ g2, const float* __restrict__ adjbf,
                          const float* __restrict__ sgi) {
  int n = blockIdx.x, b = blockIdx.y, tid = threadIdx.x;
  long ro = (long)b * 1000000 + (long)n * N_;
  float* row = g2 + ro;
  const float* brow = adjbf + ro;
  const float* grow = sgi + (long)n * N_;
  float x[4]; float s = 0.f, s2 = 0.f;
  #pragma unroll
  for (int i = 0; i < 4; ++i) {
    int idx = tid + i * 256;
    x[i] = (idx < N_) ? (row[idx] + brow[idx]) : 0.f;
    s += x[i]; s2 += x[i] * x[i];
  }
  block_red2(s, s2);
  float m1 = s * 1e-3f, v1 = s2 * 1e-3f - m1 * m1, r1 = rsqrtf(v1 + 1e-5f);
  s = 0.f; s2 = 0.f;
  #pragma unroll
  for (int i = 0; i < 4; ++i) {
    int idx = tid + i * 256;
    x[i] = (idx < N_) ? ((x[i] - m1) * r1 + grow[idx]) : 0.f;
    s += x[i]; s2 += x[i] * x[i];
  }
  block_red2(s, s2);
  float m2 = s * 1e-3f, v2 = s2 * 1e-3f - m2 * m2, r2 = rsqrtf(v2 + 1e-5f);
  float mx = -1e30f;
  #pragma unroll
  for (int i = 0; i < 4; ++i) {
    int idx = tid + i * 256;
    if (idx < N_) { x[i] = fmaxf((x[i] - m2) * r2, 0.f); mx = fmaxf(mx, x[i]); }
  }
  block_redmax(mx);
  float es = 0.f, d = 0.f;
  #pragma unroll
  for (int i = 0; i < 4; ++i) {
    int idx = tid + i * 256;
    if (idx < N_) { x[i] = __expf(x[i] - mx); es += x[i]; } else x[i] = 0.f;
  }
  block_red2(es, d);
  float inv = 1.f / es;
  #pragma unroll
  for (int i = 0; i < 4; ++i) {
    int idx = tid + i * 256;
    if (idx < N_) row[idx] = x[i] * inv;
  }
}

// ---------------- adj_static broadcast to [B,N,N] ----------------
__global__ void broadcast_static(const float* __restrict__ adjs, float* __restrict__ out1) {
  long i = (long)blockIdx.x * 256 + threadIdx.x;   // over 250,000 float4
  if (i < 250000) {
    float4 v = ((const float4*)adjs)[i];
    #pragma unroll
    for (int b = 0; b < B_; ++b) ((float4*)out1)[(long)b * 250000 + i] = v;
  }
}

__global__ void copy_s(const float* __restrict__ src, float* __restrict__ dst) {
  int i = blockIdx.x * 256 + threadIdx.x;
  if (i < N_ * DN) dst[i] = src[i];
}

// ---------------- colsum + Frobenius of adj_static ----------------
__global__ void colsum_fnorm(const float* __restrict__ adjs, float* __restrict__ colsum,
                             float* __restrict__ fnorm) {
  int m = blockIdx.x * 256 + threadIdx.x;
  float c = 0.f, f = 0.f;
  if (m < N_) {
    for (int n = 0; n < N_; ++n) { float v = adjs[(long)n * N_ + m]; c += v; f += v * v; }
    colsum[m] = c;
  }
  float d = 0.f; block_red2(f, d);
  if (threadIdx.x == 0) atomicAdd(fnorm, f);
}

// ---------------- trace term: tr[b] = sum_{n,m} A[n,m] * (x_bn · x_bm) ----------------
__global__ void trace_kernel(const float* __restrict__ adjs, const float* __restrict__ x,
                             float* __restrict__ tr) {
  int b = blockIdx.y;
  int lane = threadIdx.x & 63;
  int m0 = blockIdx.x * 32 + (threadIdx.x >> 6) * 8;   // strip of 8 columns per wave
  const float* xb = x + (long)b * (N_ * DN);
  float acc[8] = {0.f, 0.f, 0.f, 0.f, 0.f, 0.f, 0.f, 0.f};
  for (int n = 0; n < N_; ++n) {
    float xv = xb[(long)n * DN + lane];
    const float* ar = adjs + (long)n * N_ + m0;
    #pragma unroll
    for (int j = 0; j < 8; ++j)
      if (m0 + j < N_) acc[j] += ar[j] * xv;
  }
  float v = 0.f;
  #pragma unroll
  for (int j = 0; j < 8; ++j)
    if (m0 + j < N_) v += acc[j] * xb[(long)(m0 + j) * DN + lane];
  v = wred_sum(v);
  if (lane == 0) atomicAdd(&tr[b], v);
}

// ---------------- gl_loss ----------------
__global__ void gl_final(const float* __restrict__ sq, const float* __restrict__ rowsum,
                         const float* __restrict__ colsum, const float* __restrict__ tr,
                         const float* __restrict__ fnorm, float* __restrict__ gl) {
  int b = blockIdx.x, tid = threadIdx.x;
  float s = 0.f;
  for (int i = tid; i < N_; i += 256) s += sq[(long)b * N_ + i] * (rowsum[i] + colsum[i]);
  float d = 0.f; block_red2(s, d);
  if (tid == 0) gl[b] = (s - 2.f * tr[b]) * 1e-3f + fnorm[0] * 1e-3f;
}

// ---------------- launch ----------------
extern "C" void kernel_launch(void* const* d_in, const int* in_sizes, int n_in,
                              void* d_out, int out_size, void* d_ws, size_t ws_size,
                              hipStream_t stream) {
  (void)in_sizes; (void)n_in; (void)out_size; (void)ws_size;
  const float* nodevec_fusion = (const float*)d_in[0];
  const float* nodevec_s      = (const float*)d_in[1];
  const float* node_input     = (const float*)d_in[2];
  const float* nodevec_dy     = (const float*)d_in[3];
  const float* w_q            = (const float*)d_in[4];
  const float* w_k            = (const float*)d_in[5];
  const float* node_w         = (const float*)d_in[6];
  const float* mlp_w          = (const float*)d_in[7];
  const float* mlp_b          = (const float*)d_in[8];
  const float* attn_linear    = (const float*)d_in[9];
  const float* attn_linear_1  = (const float*)d_in[10];

  float* out  = (float*)d_out;
  float* out0 = out;               // adj_dynamic [16,1000,1000]; doubles as GEMM2 scratch
  float* out1 = out + 16000000;    // adj_static_b; doubles as skip_atten scratch
  float* outS = out + 32000000;    // nodevec_s copy
  float* outGL = out + 32064000;   // gl_loss[16]

  char* wp = (char*)d_ws;
  auto alloc = [&](size_t bytes) { char* p = wp; wp += (bytes + 255) & ~(size_t)255; return p; };
  float* adjs            = (float*)alloc((size_t)N_ * N_ * 4);
  float* sgi             = (float*)alloc((size_t)N_ * N_ * 4);
  float* bufbf           = (float*)alloc((size_t)B_ * N_ * N_ * 4);     // A_pre -> adj_bf
  unsigned short* tbf    = (unsigned short*)alloc((size_t)B_ * NP * NP * 2);
  unsigned short* afbf   = (unsigned short*)alloc((size_t)B_ * NP * NP * 2);
  unsigned short* L1T    = (unsigned short*)alloc((size_t)NP * NP * 2);
  unsigned short* L2T    = (unsigned short*)alloc((size_t)NP * NP * 2);
  unsigned short* nv11   = (unsigned short*)alloc((size_t)B_ * NP * DN * 2);
  unsigned short* qsb    = (unsigned short*)alloc((size_t)B_ * NP * D_ * 2);
  unsigned short* kbb    = (unsigned short*)alloc((size_t)B_ * NP * D_ * 2);
  float* sq              = (float*)alloc((size_t)B_ * N_ * 4);
  float* colsum          = (float*)alloc(4096);
  float* rowsum          = (float*)alloc(4096);
  float* weff            = (float*)alloc(256);
  float* tr              = (float*)alloc(256);
  float* fnorm           = (float*)alloc(256);

  prep_kernel<<<1, 64, 0, stream>>>(mlp_w, mlp_b, weff, tr, fnorm);
  transpose_pad<<<dim3(32, 32), dim3(32, 8), 0, stream>>>(attn_linear,   L1T);
  transpose_pad<<<dim3(32, 32), dim3(32, 8), 0, stream>>>(attn_linear_1, L2T);
  gram_kernel<<<dim3(63, 63), dim3(16, 16), 0, stream>>>(nodevec_s,  adjs);
  gram_kernel<<<dim3(63, 63), dim3(16, 16), 0, stream>>>(nodevec_dy, sgi);
  row_ln_sm<<<1000, 256, 0, stream>>>(adjs, rowsum);                       // adj_static
  row_ln<<<dim3(1000, 1), 256, 0, stream>>>(sgi, 0L);                      // static_graph_inf
  fusion_qk<<<1000, 128, 0, stream>>>(nodevec_fusion, node_w, w_q, w_k, weff, node_input,
                                      nv11, qsb, kbb, sq);
  // skip_pre = nv11 · nv11^T  -> out1 (region1 scratch)
  gemm_bt<0><<<dim3(8, 8, 16), 256, 0, stream>>>(nv11, (long)NP * DN, DN,
                                                 nv11, (long)NP * DN, DN, DN,
                                                 out1, 1000000L, (unsigned short*)nullptr, 0L);
  row_ln<<<dim3(1000, 16), 256, 0, stream>>>(out1, 1000000L);              // skip_atten
  // A_pre = qs · k^T -> bufbf
  gemm_bt<0><<<dim3(8, 8, 16), 256, 0, stream>>>(qsb, (long)NP * D_, D_,
                                                 kbb, (long)NP * D_, D_, D_,
                                                 bufbf, 1000000L, (unsigned short*)nullptr, 0L);
  row_combine1<<<dim3(1000, 16), 256, 0, stream>>>(bufbf, out1, tbf);      // adj_bf + t
  // adj_af = relu(t @ L1) -> bf16
  gemm_bt<1><<<dim3(8, 8, 16), 256, 0, stream>>>(tbf, (long)NP * NP, NP,
                                                 L1T, 0L, NP, NP,
                                                 (float*)nullptr, 0L, afbf, (long)NP * NP);
  // G2 = adj_af @ L2 -> region0 (f32)
  gemm_bt<0><<<dim3(8, 8, 16), 256, 0, stream>>>(afbf, (long)NP * NP, NP,
                                                 L2T, 0L, NP, NP,
                                                 out0, 1000000L, (unsigned short*)nullptr, 0L);
  row_final<<<dim3(1000, 16), 256, 0, stream>>>(out0, bufbf, sgi);         // adj_dynamic
  broadcast_static<<<977, 256, 0, stream>>>(adjs, out1);                   // adj_static_b
  copy_s<<<250, 256, 0, stream>>>(nodevec_s, outS);
  colsum_fnorm<<<4, 256, 0, stream>>>(adjs, colsum, fnorm);
  trace_kernel<<<dim3(32, 16), 256, 0, stream>>>(adjs, node_input, tr);
  gl_final<<<16, 256, 0, stream>>>(sq, rowsum, colsum, tr, fnorm, outGL);
}

// Round 2
// 604.471 us; speedup vs baseline: 2.0792x; 2.0792x over previous
//
#include <hip/hip_runtime.h>

// Shapes (fixed by the problem)
#define B_  16
#define N_  1000
#define NP  1024      // padded N for bf16 GEMM operands
#define DN  64
#define D_  128

typedef __attribute__((ext_vector_type(8))) short  short8;
typedef __attribute__((ext_vector_type(4))) float  f32x4;

// ---------------- helpers ----------------
__device__ __forceinline__ unsigned short f2bf(float v) {
  union { float f; unsigned int u; } c; c.f = v;
  unsigned int u = c.u;
  unsigned int r = (u + 0x7fffu + ((u >> 16) & 1u)) >> 16;   // RNE
  return (unsigned short)r;
}

__device__ __forceinline__ float wred_sum(float v) {
  #pragma unroll
  for (int o = 32; o > 0; o >>= 1) v += __shfl_down(v, o);
  return v;
}

// block-wide reductions; all callers use blockDim.x == 256 (4 waves)
__device__ __forceinline__ void block_red2(float& a, float& b) {
  __shared__ float sb[8];
  __syncthreads();
  float ra = a, rb = b;
  #pragma unroll
  for (int o = 32; o > 0; o >>= 1) { ra += __shfl_down(ra, o); rb += __shfl_down(rb, o); }
  int w = threadIdx.x >> 6;
  if ((threadIdx.x & 63) == 0) { sb[w] = ra; sb[4 + w] = rb; }
  __syncthreads();
  a = sb[0] + sb[1] + sb[2] + sb[3];
  b = sb[4] + sb[5] + sb[6] + sb[7];
}

__device__ __forceinline__ void block_redmax(float& a) {
  __shared__ float sm[4];
  __syncthreads();
  float ra = a;
  #pragma unroll
  for (int o = 32; o > 0; o >>= 1) ra = fmaxf(ra, __shfl_down(ra, o));
  if ((threadIdx.x & 63) == 0) sm[threadIdx.x >> 6] = ra;
  __syncthreads();
  a = fmaxf(fmaxf(sm[0], sm[1]), fmaxf(sm[2], sm[3]));
}

// ---------------- tiny setup: w_eff, zero tr/fnorm/colsum ----------------
__global__ void prep_kernel(const float* __restrict__ mlp_w, const float* __restrict__ mlp_b,
                            float* __restrict__ weff, float* __restrict__ tr,
                            float* __restrict__ fnorm, float* __restrict__ colsum) {
  int t = threadIdx.x;   // 1024 threads
  if (t < 8) {
    float s = 1.f;                    // +1 from the residual branch of the 1x1 conv
    for (int o = 0; o < 8; ++o) s += mlp_w[o * 8 + t];
    weff[t] = s;
  }
  if (t < 16) tr[t] = 0.f;
  if (t == 16) fnorm[0] = 0.f;
  colsum[t] = 0.f;
  (void)mlp_b;  // b_eff is added uniformly pre-LayerNorm -> shift-invariant -> no-op
}

// ---------------- transpose + cast + zero-pad: [1000x1000]f32 -> [1024x1024]bf16^T ----------------
__global__ void transpose_pad(const float* __restrict__ in, unsigned short* __restrict__ out) {
  __shared__ float tile[32][33];
  int bx = blockIdx.x * 32, by = blockIdx.y * 32;
  int tx = threadIdx.x, ty = threadIdx.y;      // (32,8)
  #pragma unroll
  for (int i = 0; i < 32; i += 8) {
    int r = by + ty + i, c = bx + tx;
    tile[ty + i][tx] = (r < N_ && c < N_) ? in[(long)r * N_ + c] : 0.f;
  }
  __syncthreads();
  #pragma unroll
  for (int i = 0; i < 32; i += 8) {
    int r = bx + ty + i, c = by + tx;          // out[r][c] = in[c][r]
    out[(long)r * NP + c] = f2bf(tile[tx][ty + i]);
  }
}

// ---------------- small gram: C[i,j] = X[i,:]·X[j,:], X [1000x64] ----------------
__global__ void gram_kernel(const float* __restrict__ X, float* __restrict__ C) {
  __shared__ float Xi[16][65], Xj[16][65];
  int tx = threadIdx.x, ty = threadIdx.y;      // (16,16)
  int i0 = blockIdx.y * 16, j0 = blockIdx.x * 16;
  #pragma unroll
  for (int kk = 0; kk < 64; kk += 16) {
    int r = i0 + ty;  Xi[ty][kk + tx] = (r < N_) ? X[(long)r * DN + kk + tx] : 0.f;
    int rj = j0 + ty; Xj[ty][kk + tx] = (rj < N_) ? X[(long)rj * DN + kk + tx] : 0.f;
  }
  __syncthreads();
  float acc = 0.f;
  #pragma unroll
  for (int d = 0; d < 64; ++d) acc += Xi[ty][d] * Xj[tx][d];
  int i = i0 + ty, j = j0 + tx;
  if (i < N_ && j < N_) C[(long)i * N_ + j] = acc;
}

// ---------------- row LayerNorm (in place), rows of length 1000 ----------------
__global__ void row_ln(float* __restrict__ base, long bstride) {
  int tid = threadIdx.x;
  float* row = base + (long)blockIdx.y * bstride + (long)blockIdx.x * N_;
  float x[4]; float s = 0.f, s2 = 0.f;
  #pragma unroll
  for (int i = 0; i < 4; ++i) {
    int idx = tid + i * 256;
    x[i] = (idx < N_) ? row[idx] : 0.f;
    s += x[i]; s2 += x[i] * x[i];
  }
  block_red2(s, s2);
  float mean = s * 1e-3f, var = s2 * 1e-3f - mean * mean;
  float r = rsqrtf(var + 1e-5f);
  #pragma unroll
  for (int i = 0; i < 4; ++i) {
    int idx = tid + i * 256;
    if (idx < N_) row[idx] = (x[i] - mean) * r;
  }
}

// ---------------- row LN -> relu -> softmax (adj_static), plus rowsum ----------------
__global__ void row_ln_sm(float* __restrict__ mat, float* __restrict__ rowsum) {
  int n = blockIdx.x, tid = threadIdx.x;
  float* row = mat + (long)n * N_;
  float x[4]; float s = 0.f, s2 = 0.f;
  #pragma unroll
  for (int i = 0; i < 4; ++i) {
    int idx = tid + i * 256;
    x[i] = (idx < N_) ? row[idx] : 0.f;
    s += x[i]; s2 += x[i] * x[i];
  }
  block_red2(s, s2);
  float mean = s * 1e-3f, var = s2 * 1e-3f - mean * mean;
  float r = rsqrtf(var + 1e-5f);
  float mx = -1e30f;
  #pragma unroll
  for (int i = 0; i < 4; ++i) {
    int idx = tid + i * 256;
    if (idx < N_) { x[i] = fmaxf((x[i] - mean) * r, 0.f); mx = fmaxf(mx, x[i]); }
  }
  block_redmax(mx);
  float es = 0.f, d = 0.f;
  #pragma unroll
  for (int i = 0; i < 4; ++i) {
    int idx = tid + i * 256;
    if (idx < N_) { x[i] = __expf(x[i] - mx); es += x[i]; } else x[i] = 0.f;
  }
  block_red2(es, d);
  float inv = 1.f / es; float ps = 0.f;
  #pragma unroll
  for (int i = 0; i < 4; ++i) {
    int idx = tid + i * 256;
    if (idx < N_) { x[i] *= inv; row[idx] = x[i]; ps += x[i]; }
  }
  d = 0.f; block_red2(ps, d);
  if (tid == 0) rowsum[n] = ps;
}

// ---------------- fusion LN + nv11 + q/k (leaky, w_eff/4 folded into q) + sq ----------------
__global__ __launch_bounds__(128)
void fusion_qk(const float* __restrict__ fus, const float* __restrict__ node_w,
               const float* __restrict__ w_q, const float* __restrict__ w_k,
               const float* __restrict__ weff, const float* __restrict__ node_input,
               unsigned short* __restrict__ nv11, unsigned short* __restrict__ qs,
               unsigned short* __restrict__ kb, float* __restrict__ sq) {
  __shared__ float wq_s[DN * D_];
  __shared__ float wk_s[DN * D_];
  __shared__ float f_s[DN];
  __shared__ float red_s[2];
  int tid = threadIdx.x;
  for (int i = tid; i < DN * D_; i += 128) { wq_s[i] = w_q[i]; wk_s[i] = w_k[i]; }
  float we = weff[tid >> 4] * 0.25f;   // per-head scale / sqrt(hd)
  __syncthreads();
  for (int r = 0; r < 16; ++r) {
    int row_id = blockIdx.x * 16 + r;           // 0..15999
    int b = row_id / N_, n = row_id % N_;
    if (tid < 64) {
      float xv = fus[(long)row_id * DN + tid];
      float s = xv, s2 = xv * xv;
      #pragma unroll
      for (int o = 32; o > 0; o >>= 1) { s += __shfl_down(s, o); s2 += __shfl_down(s2, o); }
      s = __shfl(s, 0); s2 = __shfl(s2, 0);
      float mean = s * (1.f / DN);
      float var  = s2 * (1.f / DN) - mean * mean;
      float rln  = rsqrtf(var + 1e-5f);
      float fv = (xv - mean) * rln;
      f_s[tid] = fv;
      float rs = fv;
      #pragma unroll
      for (int o = 32; o > 0; o >>= 1) rs += __shfl_down(rs, o);
      if (tid == 0) red_s[0] = rs;
      float xi = node_input[(long)row_id * DN + tid];
      float q2 = xi * xi;
      #pragma unroll
      for (int o = 32; o > 0; o >>= 1) q2 += __shfl_down(q2, o);
      if (tid == 0) sq[row_id] = q2;
    }
    __syncthreads();
    if (tid < 64) {
      float v = red_s[0] * node_w[(long)n * DN + tid] + f_s[tid];
      nv11[((long)b * NP + n) * DN + tid] = f2bf(v);
    }
    float aq = 0.f, ak = 0.f;
    #pragma unroll 8
    for (int d = 0; d < DN; ++d) {
      float fv = f_s[d];
      aq += fv * wq_s[d * D_ + tid];
      ak += fv * wk_s[d * D_ + tid];
    }
    aq = (aq > 0.f) ? aq : 0.01f * aq;    // leaky_relu
    ak = (ak > 0.f) ? ak : 0.01f * ak;
    qs[((long)b * NP + n) * D_ + tid] = f2bf(aq * we);
    kb[((long)b * NP + n) * D_ + tid] = f2bf(ak);
    __syncthreads();
  }
}

// ---------------- batched bf16 MFMA GEMM: C[b] = X[b] · Y[b]^T (m97-style 128^2 tile) ----------------
#define GLOAD_LDS16(gp, lp) \
  __builtin_amdgcn_global_load_lds((const __attribute__((address_space(1))) void*)(gp), \
                                   (__attribute__((address_space(3))) void*)(lp), 16, 0, 0)

// EPI 0: bounds-checked f32 store, stride 1000.  EPI 1: relu -> bf16 full-tile store, stride 1024.
template<int EPI>
__global__ __launch_bounds__(256, 2)
void gemm_bt(const unsigned short* __restrict__ X, long xbs, int ldx,
             const unsigned short* __restrict__ Y, long ybs, int ldy,
             int K,
             float* __restrict__ outF, long obsF,
             unsigned short* __restrict__ outB, long obsB) {
  __shared__ __align__(16) short As[128 * 32];
  __shared__ __align__(16) short Bs[128 * 32];
  const int tid = threadIdx.x;
  const int b  = blockIdx.z;
  const int m0 = blockIdx.x * 128;
  const int n0 = blockIdx.y * 128;
  const unsigned short* Xb = X + (long)b * xbs + (long)m0 * ldx;
  const unsigned short* Yb = Y + (long)b * ybs + (long)n0 * ldy;

  const int lane = tid & 63, w = tid >> 6;
  const int wm = (w >> 1) * 64, wn = (w & 1) * 64;   // 2x2 waves -> 64x64 each
  const int fr = lane & 15, kg = lane >> 4;

  // staging map: thread -> (row sr, k-slot ks); source column XOR-swizzled so that
  // LDS[row][slot] = X[row][(slot ^ p_row)*8 ..], p_row = (row>>1)&3  (rule 21: same involution on read)
  const int sr = tid >> 2;
  const int ks = tid & 3;
  const int c1 = ((ks ^ ((sr >> 1) & 3)) * 8);
  const int c2 = ((ks ^ (((sr + 64) >> 1) & 3)) * 8);

  f32x4 acc[4][4];
  #pragma unroll
  for (int mi = 0; mi < 4; ++mi)
    #pragma unroll
    for (int ni = 0; ni < 4; ++ni)
      acc[mi][ni] = (f32x4){0.f, 0.f, 0.f, 0.f};

  const short* Asp = (const short*)As;
  const short* Bsp = (const short*)Bs;

  for (int k0 = 0; k0 < K; k0 += 32) {
    GLOAD_LDS16(Xb + (long)sr * ldx + k0 + c1,        (char*)As + tid * 16);
    GLOAD_LDS16(Xb + (long)(sr + 64) * ldx + k0 + c2, (char*)As + 4096 + tid * 16);
    GLOAD_LDS16(Yb + (long)sr * ldy + k0 + c1,        (char*)Bs + tid * 16);
    GLOAD_LDS16(Yb + (long)(sr + 64) * ldy + k0 + c2, (char*)Bs + 4096 + tid * 16);
    __syncthreads();   // compiler emits s_waitcnt vmcnt(0) before s_barrier -> LDS valid
    short8 av[4], bv[4];
    #pragma unroll
    for (int mi = 0; mi < 4; ++mi) {
      int r = wm + mi * 16 + fr;
      av[mi] = *(const short8*)&Asp[r * 32 + ((kg ^ ((r >> 1) & 3)) * 8)];
    }
    #pragma unroll
    for (int ni = 0; ni < 4; ++ni) {
      int r = wn + ni * 16 + fr;
      bv[ni] = *(const short8*)&Bsp[r * 32 + ((kg ^ ((r >> 1) & 3)) * 8)];
    }
    #pragma unroll
    for (int mi = 0; mi < 4; ++mi)
      #pragma unroll
      for (int ni = 0; ni < 4; ++ni)
        acc[mi][ni] = __builtin_amdgcn_mfma_f32_16x16x32_bf16(av[mi], bv[ni], acc[mi][ni], 0, 0, 0);
    __syncthreads();   // protect LDS from next-iter staging
  }

  // C/D layout (m89-verified): col = lane&15, row = (lane>>4)*4 + reg
  if (EPI == 0) {
    float* ob = outF + (long)b * obsF;
    #pragma unroll
    for (int mi = 0; mi < 4; ++mi) {
      #pragma unroll
      for (int ni = 0; ni < 4; ++ni) {
        int col  = n0 + wn + ni * 16 + fr;
        int rowb = m0 + wm + mi * 16 + kg * 4;
        #pragma unroll
        for (int j = 0; j < 4; ++j) {
          int row = rowb + j;
          if (row < N_ && col < N_) ob[(long)row * N_ + col] = acc[mi][ni][j];
        }
      }
    }
  } else {
    unsigned short* ob = outB + (long)b * obsB;
    #pragma unroll
    for (int mi = 0; mi < 4; ++mi) {
      #pragma unroll
      for (int ni = 0; ni < 4; ++ni) {
        int col  = n0 + wn + ni * 16 + fr;
        int rowb = m0 + wm + mi * 16 + kg * 4;
        #pragma unroll
        for (int j = 0; j < 4; ++j) {
          int row = rowb + j;
          ob[(long)row * NP + col] = f2bf(fmaxf(acc[mi][ni][j], 0.f));
        }
      }
    }
  }
}

// ---------------- adj_bf = ln(A_pre)+skip (in place), t = bf16(ln(adj_bf)) zero-padded ----------------
__global__ void row_combine1(float* __restrict__ apre, const float* __restrict__ skip,
                             unsigned short* __restrict__ t) {
  int n = blockIdx.x, b = blockIdx.y, tid = threadIdx.x;
  long ro = (long)b * 1000000 + (long)n * N_;
  float* arow = apre + ro;
  const float* srow = skip + ro;
  float x[4]; float s = 0.f, s2 = 0.f;
  #pragma unroll
  for (int i = 0; i < 4; ++i) {
    int idx = tid + i * 256;
    x[i] = (idx < N_) ? arow[idx] : 0.f;
    s += x[i]; s2 += x[i] * x[i];
  }
  block_red2(s, s2);
  float mean = s * 1e-3f, var = s2 * 1e-3f - mean * mean;
  float r = rsqrtf(var + 1e-5f);
  float y[4]; s = 0.f; s2 = 0.f;
  #pragma unroll
  for (int i = 0; i < 4; ++i) {
    int idx = tid + i * 256;
    if (idx < N_) { y[i] = (x[i] - mean) * r + srow[idx]; arow[idx] = y[i]; }
    else y[i] = 0.f;
    s += y[i]; s2 += y[i] * y[i];
  }
  block_red2(s, s2);
  float mean2 = s * 1e-3f, var2 = s2 * 1e-3f - mean2 * mean2;
  float r2 = rsqrtf(var2 + 1e-5f);
  unsigned short* trow = t + ((long)b * NP + n) * NP;
  #pragma unroll
  for (int i = 0; i < 4; ++i) {
    int idx = tid + i * 256;                     // covers 0..1023
    float v = (idx < N_) ? (y[i] - mean2) * r2 : 0.f;
    trow[idx] = f2bf(v);
  }
}

// ---------------- final chain: ln(G2+adj_bf); +sgi; ln; relu; softmax -> in place on region0 ----------------
__global__ void row_final(float* __restrict__ g2, const float* __restrict__ adjbf,
                          const float* __restrict__ sgi) {
  int n = blockIdx.x, b = blockIdx.y, tid = threadIdx.x;
  long ro = (long)b * 1000000 + (long)n * N_;
  float* row = g2 + ro;
  const float* brow = adjbf + ro;
  const float* grow = sgi + (long)n * N_;
  float x[4]; float s = 0.f, s2 = 0.f;
  #pragma unroll
  for (int i = 0; i < 4; ++i) {
    int idx = tid + i * 256;
    x[i] = (idx < N_) ? (row[idx] + brow[idx]) : 0.f;
    s += x[i]; s2 += x[i] * x[i];
  }
  block_red2(s, s2);
  float m1 = s * 1e-3f, v1 = s2 * 1e-3f - m1 * m1, r1 = rsqrtf(v1 + 1e-5f);
  s = 0.f; s2 = 0.f;
  #pragma unroll
  for (int i = 0; i < 4; ++i) {
    int idx = tid + i * 256;
    x[i] = (idx < N_) ? ((x[i] - m1) * r1 + grow[idx]) : 0.f;
    s += x[i]; s2 += x[i] * x[i];
  }
  block_red2(s, s2);
  float m2 = s * 1e-3f, v2 = s2 * 1e-3f - m2 * m2, r2 = rsqrtf(v2 + 1e-5f);
  float mx = -1e30f;
  #pragma unroll
  for (int i = 0; i < 4; ++i) {
    int idx = tid + i * 256;
    if (idx < N_) { x[i] = fmaxf((x[i] - m2) * r2, 0.f); mx = fmaxf(mx, x[i]); }
  }
  block_redmax(mx);
  float es = 0.f, d = 0.f;
  #pragma unroll
  for (int i = 0; i < 4; ++i) {
    int idx = tid + i * 256;
    if (idx < N_) { x[i] = __expf(x[i] - mx); es += x[i]; } else x[i] = 0.f;
  }
  block_red2(es, d);
  float inv = 1.f / es;
  #pragma unroll
  for (int i = 0; i < 4; ++i) {
    int idx = tid + i * 256;
    if (idx < N_) row[idx] = x[i] * inv;
  }
}

// ---------------- adj_static broadcast to [B,N,N] ----------------
__global__ void broadcast_static(const float* __restrict__ adjs, float* __restrict__ out1) {
  long i = (long)blockIdx.x * 256 + threadIdx.x;   // over 250,000 float4
  if (i < 250000) {
    float4 v = ((const float4*)adjs)[i];
    #pragma unroll
    for (int b = 0; b < B_; ++b) ((float4*)out1)[(long)b * 250000 + i] = v;
  }
}

__global__ void copy_s(const float* __restrict__ src, float* __restrict__ dst) {
  int i = blockIdx.x * 256 + threadIdx.x;
  if (i < N_ * DN) dst[i] = src[i];
}

// ---------------- colsum + Frobenius of adj_static (segmented, atomic-accumulated) ----------------
__global__ void colsum_fnorm(const float* __restrict__ adjs, float* __restrict__ colsum,
                             float* __restrict__ fnorm) {
  int m = blockIdx.x * 256 + threadIdx.x;      // 0..1023
  int n0 = blockIdx.y * 63;                    // 16 segments x 63 rows >= 1000
  int ne = min(n0 + 63, N_);
  float c = 0.f, f = 0.f;
  if (m < N_) {
    for (int n = n0; n < ne; ++n) { float v = adjs[(long)n * N_ + m]; c += v; f += v * v; }
    atomicAdd(&colsum[m], c);
  }
  float d = 0.f; block_red2(f, d);
  if (threadIdx.x == 0) atomicAdd(fnorm, f);
}

// ---------------- trace term: tr[b] += sum_{m,d} (A^T X_b)[m,d] * X_b[m,d]  ----------------
// grid (16 m-tiles, 16 b, 4 n-segments); block 256 = 16x16 threads, 4x4 register tile.
__global__ __launch_bounds__(256)
void trace_kernel(const float* __restrict__ adjs, const float* __restrict__ x,
                  float* __restrict__ tr) {
  __shared__ float A_s[64 * 64];
  __shared__ float X_s[64 * 64];
  const int tid = threadIdx.x;
  const int tx = tid & 15, ty = tid >> 4;
  const int m0 = blockIdx.x * 64;
  const int b  = blockIdx.y;
  const int nseg = blockIdx.z;
  const float* xb = x + (long)b * (N_ * DN);

  float acc[4][4];
  #pragma unroll
  for (int i = 0; i < 4; ++i)
    #pragma unroll
    for (int j = 0; j < 4; ++j) acc[i][j] = 0.f;

  for (int cc = 0; cc < 4; ++cc) {
    int n0 = (nseg * 4 + cc) * 64;
    // stage A[n0+nn][m0+cm] and X[n0+nn][cm]; coalesced scalar loads, masked
    #pragma unroll
    for (int k = 0; k < 16; ++k) {
      int i = tid + k * 256;                 // 0..4095
      int nn = i >> 6, cm = i & 63;
      int n = n0 + nn;
      A_s[i] = (n < N_ && (m0 + cm) < N_) ? adjs[(long)n * N_ + m0 + cm] : 0.f;
      X_s[i] = (n < N_) ? xb[(long)n * DN + cm] : 0.f;
    }
    __syncthreads();
    #pragma unroll 8
    for (int nn = 0; nn < 64; ++nn) {
      float4 av = *(const float4*)&A_s[nn * 64 + ty * 4];   // m-direction
      float4 xv = *(const float4*)&X_s[nn * 64 + tx * 4];   // d-direction
      #pragma unroll
      for (int i = 0; i < 4; ++i) {
        float a = (&av.x)[i];
        acc[i][0] += a * xv.x;
        acc[i][1] += a * xv.y;
        acc[i][2] += a * xv.z;
        acc[i][3] += a * xv.w;
      }
    }
    __syncthreads();
  }

  // dot partial Y-tile with X[m][d]
  float v = 0.f;
  #pragma unroll
  for (int i = 0; i < 4; ++i) {
    int m = m0 + ty * 4 + i;
    if (m < N_) {
      float4 xm = *(const float4*)&xb[(long)m * DN + tx * 4];
      v += acc[i][0] * xm.x + acc[i][1] * xm.y + acc[i][2] * xm.z + acc[i][3] * xm.w;
    }
  }
  float d = 0.f; block_red2(v, d);
  if (tid == 0) atomicAdd(&tr[b], v);
}

// ---------------- gl_loss ----------------
__global__ void gl_final(const float* __restrict__ sq, const float* __restrict__ rowsum,
                         const float* __restrict__ colsum, const float* __restrict__ tr,
                         const float* __restrict__ fnorm, float* __restrict__ gl) {
  int b = blockIdx.x, tid = threadIdx.x;
  float s = 0.f;
  for (int i = tid; i < N_; i += 256) s += sq[(long)b * N_ + i] * (rowsum[i] + colsum[i]);
  float d = 0.f; block_red2(s, d);
  if (tid == 0) gl[b] = (s - 2.f * tr[b]) * 1e-3f + fnorm[0] * 1e-3f;
}

// ---------------- launch ----------------
extern "C" void kernel_launch(void* const* d_in, const int* in_sizes, int n_in,
                              void* d_out, int out_size, void* d_ws, size_t ws_size,
                              hipStream_t stream) {
  (void)in_sizes; (void)n_in; (void)out_size; (void)ws_size;
  const float* nodevec_fusion = (const float*)d_in[0];
  const float* nodevec_s      = (const float*)d_in[1];
  const float* node_input     = (const float*)d_in[2];
  const float* nodevec_dy     = (const float*)d_in[3];
  const float* w_q            = (const float*)d_in[4];
  const float* w_k            = (const float*)d_in[5];
  const float* node_w         = (const float*)d_in[6];
  const float* mlp_w          = (const float*)d_in[7];
  const float* mlp_b          = (const float*)d_in[8];
  const float* attn_linear    = (const float*)d_in[9];
  const float* attn_linear_1  = (const float*)d_in[10];

  float* out  = (float*)d_out;
  float* out0 = out;               // adj_dynamic [16,1000,1000]; doubles as GEMM2 scratch
  float* out1 = out + 16000000;    // adj_static_b; doubles as skip_atten scratch
  float* outS = out + 32000000;    // nodevec_s copy
  float* outGL = out + 32064000;   // gl_loss[16]

  char* wp = (char*)d_ws;
  auto alloc = [&](size_t bytes) { char* p = wp; wp += (bytes + 255) & ~(size_t)255; return p; };
  float* adjs            = (float*)alloc((size_t)N_ * N_ * 4);
  float* sgi             = (float*)alloc((size_t)N_ * N_ * 4);
  float* bufbf           = (float*)alloc((size_t)B_ * N_ * N_ * 4);     // A_pre -> adj_bf
  unsigned short* tbf    = (unsigned short*)alloc((size_t)B_ * NP * NP * 2);
  unsigned short* afbf   = (unsigned short*)alloc((size_t)B_ * NP * NP * 2);
  unsigned short* L1T    = (unsigned short*)alloc((size_t)NP * NP * 2);
  unsigned short* L2T    = (unsigned short*)alloc((size_t)NP * NP * 2);
  unsigned short* nv11   = (unsigned short*)alloc((size_t)B_ * NP * DN * 2);
  unsigned short* qsb    = (unsigned short*)alloc((size_t)B_ * NP * D_ * 2);
  unsigned short* kbb    = (unsigned short*)alloc((size_t)B_ * NP * D_ * 2);
  float* sq              = (float*)alloc((size_t)B_ * N_ * 4);
  float* colsum          = (float*)alloc(4096);
  float* rowsum          = (float*)alloc(4096);
  float* weff            = (float*)alloc(256);
  float* tr              = (float*)alloc(256);
  float* fnorm           = (float*)alloc(256);

  prep_kernel<<<1, 1024, 0, stream>>>(mlp_w, mlp_b, weff, tr, fnorm, colsum);
  transpose_pad<<<dim3(32, 32), dim3(32, 8), 0, stream>>>(attn_linear,   L1T);
  transpose_pad<<<dim3(32, 32), dim3(32, 8), 0, stream>>>(attn_linear_1, L2T);
  gram_kernel<<<dim3(63, 63), dim3(16, 16), 0, stream>>>(nodevec_s,  adjs);
  gram_kernel<<<dim3(63, 63), dim3(16, 16), 0, stream>>>(nodevec_dy, sgi);
  row_ln_sm<<<1000, 256, 0, stream>>>(adjs, rowsum);                       // adj_static
  row_ln<<<dim3(1000, 1), 256, 0, stream>>>(sgi, 0L);                      // static_graph_inf
  fusion_qk<<<1000, 128, 0, stream>>>(nodevec_fusion, node_w, w_q, w_k, weff, node_input,
                                      nv11, qsb, kbb, sq);
  // skip_pre = nv11 · nv11^T  -> out1 (region1 scratch)
  gemm_bt<0><<<dim3(8, 8, 16), 256, 0, stream>>>(nv11, (long)NP * DN, DN,
                                                 nv11, (long)NP * DN, DN, DN,
                                                 out1, 1000000L, (unsigned short*)nullptr, 0L);
  row_ln<<<dim3(1000, 16), 256, 0, stream>>>(out1, 1000000L);              // skip_atten
  // A_pre = qs · k^T -> bufbf
  gemm_bt<0><<<dim3(8, 8, 16), 256, 0, stream>>>(qsb, (long)NP * D_, D_,
                                                 kbb, (long)NP * D_, D_, D_,
                                                 bufbf, 1000000L, (unsigned short*)nullptr, 0L);
  row_combine1<<<dim3(1000, 16), 256, 0, stream>>>(bufbf, out1, tbf);      // adj_bf + t
  // adj_af = relu(t @ L1) -> bf16
  gemm_bt<1><<<dim3(8, 8, 16), 256, 0, stream>>>(tbf, (long)NP * NP, NP,
                                                 L1T, 0L, NP, NP,
                                                 (float*)nullptr, 0L, afbf, (long)NP * NP);
  // G2 = adj_af @ L2 -> region0 (f32)
  gemm_bt<0><<<dim3(8, 8, 16), 256, 0, stream>>>(afbf, (long)NP * NP, NP,
                                                 L2T, 0L, NP, NP,
                                                 out0, 1000000L, (unsigned short*)nullptr, 0L);
  row_final<<<dim3(1000, 16), 256, 0, stream>>>(out0, bufbf, sgi);         // adj_dynamic
  broadcast_static<<<977, 256, 0, stream>>>(adjs, out1);                   // adj_static_b
  copy_s<<<250, 256, 0, stream>>>(nodevec_s, outS);
  colsum_fnorm<<<dim3(4, 16), 256, 0, stream>>>(adjs, colsum, fnorm);
  trace_kernel<<<dim3(16, 16, 4), 256, 0, stream>>>(adjs, node_input, tr);
  gl_final<<<16, 256, 0, stream>>>(sq, rowsum, colsum, tr, fnorm, outGL);
}

// Round 4
// 538.594 us; speedup vs baseline: 2.3336x; 1.1223x over previous
//
#include <hip/hip_runtime.h>

// Shapes (fixed by the problem)
#define B_  16
#define N_  1000
#define NP  1024      // padded N for bf16 GEMM operands
#define DN  64
#define D_  128

typedef __attribute__((ext_vector_type(8))) short  short8;
typedef __attribute__((ext_vector_type(4))) float  f32x4;

// ---------------- helpers ----------------
__device__ __forceinline__ unsigned short f2bf(float v) {
  union { float f; unsigned int u; } c; c.f = v;
  unsigned int u = c.u;
  unsigned int r = (u + 0x7fffu + ((u >> 16) & 1u)) >> 16;   // RNE
  return (unsigned short)r;
}

// block-wide reductions; all callers use blockDim.x == 256 (4 waves)
__device__ __forceinline__ void block_red2(float& a, float& b) {
  __shared__ float sb[8];
  __syncthreads();
  float ra = a, rb = b;
  #pragma unroll
  for (int o = 32; o > 0; o >>= 1) { ra += __shfl_down(ra, o); rb += __shfl_down(rb, o); }
  int w = threadIdx.x >> 6;
  if ((threadIdx.x & 63) == 0) { sb[w] = ra; sb[4 + w] = rb; }
  __syncthreads();
  a = sb[0] + sb[1] + sb[2] + sb[3];
  b = sb[4] + sb[5] + sb[6] + sb[7];
}

__device__ __forceinline__ void block_redmax(float& a) {
  __shared__ float sm[4];
  __syncthreads();
  float ra = a;
  #pragma unroll
  for (int o = 32; o > 0; o >>= 1) ra = fmaxf(ra, __shfl_down(ra, o));
  if ((threadIdx.x & 63) == 0) sm[threadIdx.x >> 6] = ra;
  __syncthreads();
  a = fmaxf(fmaxf(sm[0], sm[1]), fmaxf(sm[2], sm[3]));
}

// ---------------- tiny setup: w_eff, wt = [w_q^T ; w_k^T] bf16, zero tr/fnorm/colsum ----------------
__global__ void prep_kernel(const float* __restrict__ mlp_w, const float* __restrict__ mlp_b,
                            const float* __restrict__ w_q, const float* __restrict__ w_k,
                            float* __restrict__ weff, float* __restrict__ tr,
                            float* __restrict__ fnorm, float* __restrict__ colsum,
                            unsigned short* __restrict__ wt) {
  int t = threadIdx.x;   // 1024 threads
  if (t < 8) {
    float s = 1.f;                    // +1 from the residual branch of the 1x1 conv
    for (int o = 0; o < 8; ++o) s += mlp_w[o * 8 + t];
    weff[t] = s;
  }
  if (t < 16) tr[t] = 0.f;
  if (t == 16) fnorm[0] = 0.f;
  colsum[t] = 0.f;
  // wt[col][d] = w_q[d][col] (col<128) or w_k[d][col-128]
  for (int i = t; i < 256 * 64; i += 1024) {
    int col = i >> 6, d = i & 63;
    float v = (col < 128) ? w_q[d * D_ + col] : w_k[d * D_ + (col - 128)];
    wt[i] = f2bf(v);
  }
  (void)mlp_b;  // b_eff is added uniformly pre-LayerNorm -> shift-invariant -> no-op
}

// ---------------- transpose + cast + zero-pad: [1000x1000]f32 -> [1024x1024]bf16^T ----------------
__global__ void transpose_pad(const float* __restrict__ in, unsigned short* __restrict__ out) {
  __shared__ float tile[32][33];
  int bx = blockIdx.x * 32, by = blockIdx.y * 32;
  int tx = threadIdx.x, ty = threadIdx.y;      // (32,8)
  #pragma unroll
  for (int i = 0; i < 32; i += 8) {
    int r = by + ty + i, c = bx + tx;
    tile[ty + i][tx] = (r < N_ && c < N_) ? in[(long)r * N_ + c] : 0.f;
  }
  __syncthreads();
  #pragma unroll
  for (int i = 0; i < 32; i += 8) {
    int r = bx + ty + i, c = by + tx;          // out[r][c] = in[c][r]
    out[(long)r * NP + c] = f2bf(tile[tx][ty + i]);
  }
}

// ---------------- small gram: C[i,j] = X[i,:]·X[j,:], X [1000x64] ----------------
__global__ void gram_kernel(const float* __restrict__ X, float* __restrict__ C) {
  __shared__ float Xi[16][65], Xj[16][65];
  int tx = threadIdx.x, ty = threadIdx.y;      // (16,16)
  int i0 = blockIdx.y * 16, j0 = blockIdx.x * 16;
  #pragma unroll
  for (int kk = 0; kk < 64; kk += 16) {
    int r = i0 + ty;  Xi[ty][kk + tx] = (r < N_) ? X[(long)r * DN + kk + tx] : 0.f;
    int rj = j0 + ty; Xj[ty][kk + tx] = (rj < N_) ? X[(long)rj * DN + kk + tx] : 0.f;
  }
  __syncthreads();
  float acc = 0.f;
  #pragma unroll
  for (int d = 0; d < 64; ++d) acc += Xi[ty][d] * Xj[tx][d];
  int i = i0 + ty, j = j0 + tx;
  if (i < N_ && j < N_) C[(long)i * N_ + j] = acc;
}

// ---------------- row LayerNorm (in place), rows of length 1000 ----------------
__global__ void row_ln(float* __restrict__ base, long bstride) {
  int tid = threadIdx.x;
  float* row = base + (long)blockIdx.y * bstride + (long)blockIdx.x * N_;
  float x[4]; float s = 0.f, s2 = 0.f;
  #pragma unroll
  for (int i = 0; i < 4; ++i) {
    int idx = tid + i * 256;
    x[i] = (idx < N_) ? row[idx] : 0.f;
    s += x[i]; s2 += x[i] * x[i];
  }
  block_red2(s, s2);
  float mean = s * 1e-3f, var = s2 * 1e-3f - mean * mean;
  float r = rsqrtf(var + 1e-5f);
  #pragma unroll
  for (int i = 0; i < 4; ++i) {
    int idx = tid + i * 256;
    if (idx < N_) row[idx] = (x[i] - mean) * r;
  }
}

// ---------------- row LN -> relu -> softmax (adj_static), plus rowsum ----------------
__global__ void row_ln_sm(float* __restrict__ mat, float* __restrict__ rowsum) {
  int n = blockIdx.x, tid = threadIdx.x;
  float* row = mat + (long)n * N_;
  float x[4]; float s = 0.f, s2 = 0.f;
  #pragma unroll
  for (int i = 0; i < 4; ++i) {
    int idx = tid + i * 256;
    x[i] = (idx < N_) ? row[idx] : 0.f;
    s += x[i]; s2 += x[i] * x[i];
  }
  block_red2(s, s2);
  float mean = s * 1e-3f, var = s2 * 1e-3f - mean * mean;
  float r = rsqrtf(var + 1e-5f);
  float mx = -1e30f;
  #pragma unroll
  for (int i = 0; i < 4; ++i) {
    int idx = tid + i * 256;
    if (idx < N_) { x[i] = fmaxf((x[i] - mean) * r, 0.f); mx = fmaxf(mx, x[i]); }
  }
  block_redmax(mx);
  float es = 0.f, d = 0.f;
  #pragma unroll
  for (int i = 0; i < 4; ++i) {
    int idx = tid + i * 256;
    if (idx < N_) { x[i] = __expf(x[i] - mx); es += x[i]; } else x[i] = 0.f;
  }
  block_red2(es, d);
  float inv = 1.f / es; float ps = 0.f;
  #pragma unroll
  for (int i = 0; i < 4; ++i) {
    int idx = tid + i * 256;
    if (idx < N_) { x[i] *= inv; row[idx] = x[i]; ps += x[i]; }
  }
  d = 0.f; block_red2(ps, d);
  if (tid == 0) rowsum[n] = ps;
}

// ---------------- fusion LN (one wave per row), nv11, sq; zero-padded bf16 outputs ----------------
__global__ __launch_bounds__(256)
void fusion_ln(const float* __restrict__ fus, const float* __restrict__ node_w,
               const float* __restrict__ node_input,
               unsigned short* __restrict__ fbf, unsigned short* __restrict__ nv11,
               float* __restrict__ sq) {
  int wid = blockIdx.x * 4 + (threadIdx.x >> 6);   // 0..1023
  int lane = threadIdx.x & 63;
  #pragma unroll 1
  for (int r = 0; r < 16; ++r) {
    int row = wid * 16 + r;                        // padded row space [16384]
    int b = row >> 10, n = row & 1023;
    long po = (long)row * DN + lane;
    if (n < N_) {
      long io = ((long)b * N_ + n) * DN + lane;
      float xv = fus[io];
      float s = xv, s2 = xv * xv;
      #pragma unroll
      for (int o = 32; o > 0; o >>= 1) { s += __shfl_xor(s, o); s2 += __shfl_xor(s2, o); }
      float mean = s * (1.f / DN);
      float var  = s2 * (1.f / DN) - mean * mean;
      float fv = (xv - mean) * rsqrtf(var + 1e-5f);
      float rs = fv;
      #pragma unroll
      for (int o = 32; o > 0; o >>= 1) rs += __shfl_xor(rs, o);
      fbf[po]  = f2bf(fv);
      nv11[po] = f2bf(rs * node_w[(long)n * DN + lane] + fv);
      float xi = node_input[io];
      float q2 = xi * xi;
      #pragma unroll
      for (int o = 32; o > 0; o >>= 1) q2 += __shfl_xor(q2, o);
      if (lane == 0) sq[(long)b * N_ + n] = q2;
    } else {
      fbf[po] = 0; nv11[po] = 0;
    }
  }
}

// ---------------- batched bf16 MFMA GEMM: C[b] = X[b] · Y[b]^T (m97-style 128^2 tile) ----------------
#define GLOAD_LDS16(gp, lp) \
  __builtin_amdgcn_global_load_lds((const __attribute__((address_space(1))) void*)(gp), \
                                   (__attribute__((address_space(3))) void*)(lp), 16, 0, 0)

// EPI 0: bounds-checked f32 store, stride 1000.
// EPI 1: relu -> bf16 full-tile store, stride 1024.
// EPI 2: q/k epilogue -> leaky_relu; q cols (<128) scaled by weff*0.25; bf16, row stride 256.
template<int EPI>
__global__ __launch_bounds__(256, 2)
void gemm_bt(const unsigned short* __restrict__ X, long xbs, int ldx,
             const unsigned short* __restrict__ Y, long ybs, int ldy,
             int K,
             float* __restrict__ outF, long obsF,
             unsigned short* __restrict__ outB, long obsB,
             const float* __restrict__ weff) {
  __shared__ __align__(16) short As[128 * 32];
  __shared__ __align__(16) short Bs[128 * 32];
  const int tid = threadIdx.x;
  const int b  = blockIdx.z;
  const int m0 = blockIdx.x * 128;
  const int n0 = blockIdx.y * 128;
  const unsigned short* Xb = X + (long)b * xbs + (long)m0 * ldx;
  const unsigned short* Yb = Y + (long)b * ybs + (long)n0 * ldy;

  const int lane = tid & 63, w = tid >> 6;
  const int wm = (w >> 1) * 64, wn = (w & 1) * 64;   // 2x2 waves -> 64x64 each
  const int fr = lane & 15, kg = lane >> 4;

  // staging map: thread -> (row sr, k-slot ks); source column XOR-swizzled so that
  // LDS[row][slot] = X[row][(slot ^ p_row)*8 ..], p_row = (row>>1)&3  (rule 21: same involution on read)
  const int sr = tid >> 2;
  const int ks = tid & 3;
  const int c1 = ((ks ^ ((sr >> 1) & 3)) * 8);
  const int c2 = ((ks ^ (((sr + 64) >> 1) & 3)) * 8);

  f32x4 acc[4][4];
  #pragma unroll
  for (int mi = 0; mi < 4; ++mi)
    #pragma unroll
    for (int ni = 0; ni < 4; ++ni)
      acc[mi][ni] = (f32x4){0.f, 0.f, 0.f, 0.f};

  const short* Asp = (const short*)As;
  const short* Bsp = (const short*)Bs;

  for (int k0 = 0; k0 < K; k0 += 32) {
    GLOAD_LDS16(Xb + (long)sr * ldx + k0 + c1,        (char*)As + tid * 16);
    GLOAD_LDS16(Xb + (long)(sr + 64) * ldx + k0 + c2, (char*)As + 4096 + tid * 16);
    GLOAD_LDS16(Yb + (long)sr * ldy + k0 + c1,        (char*)Bs + tid * 16);
    GLOAD_LDS16(Yb + (long)(sr + 64) * ldy + k0 + c2, (char*)Bs + 4096 + tid * 16);
    __syncthreads();   // compiler emits s_waitcnt vmcnt(0) before s_barrier -> LDS valid
    short8 av[4], bv[4];
    #pragma unroll
    for (int mi = 0; mi < 4; ++mi) {
      int r = wm + mi * 16 + fr;
      av[mi] = *(const short8*)&Asp[r * 32 + ((kg ^ ((r >> 1) & 3)) * 8)];
    }
    #pragma unroll
    for (int ni = 0; ni < 4; ++ni) {
      int r = wn + ni * 16 + fr;
      bv[ni] = *(const short8*)&Bsp[r * 32 + ((kg ^ ((r >> 1) & 3)) * 8)];
    }
    #pragma unroll
    for (int mi = 0; mi < 4; ++mi)
      #pragma unroll
      for (int ni = 0; ni < 4; ++ni)
        acc[mi][ni] = __builtin_amdgcn_mfma_f32_16x16x32_bf16(av[mi], bv[ni], acc[mi][ni], 0, 0, 0);
    __syncthreads();   // protect LDS from next-iter staging
  }

  // C/D layout (m89-verified): col = lane&15, row = (lane>>4)*4 + reg
  if (EPI == 0) {
    float* ob = outF + (long)b * obsF;
    #pragma unroll
    for (int mi = 0; mi < 4; ++mi) {
      #pragma unroll
      for (int ni = 0; ni < 4; ++ni) {
        int col  = n0 + wn + ni * 16 + fr;
        int rowb = m0 + wm + mi * 16 + kg * 4;
        #pragma unroll
        for (int j = 0; j < 4; ++j) {
          int row = rowb + j;
          if (row < N_ && col < N_) ob[(long)row * N_ + col] = acc[mi][ni][j];
        }
      }
    }
  } else if (EPI == 1) {
    unsigned short* ob = outB + (long)b * obsB;
    #pragma unroll
    for (int mi = 0; mi < 4; ++mi) {
      #pragma unroll
      for (int ni = 0; ni < 4; ++ni) {
        int col  = n0 + wn + ni * 16 + fr;
        int rowb = m0 + wm + mi * 16 + kg * 4;
        #pragma unroll
        for (int j = 0; j < 4; ++j) {
          int row = rowb + j;
          ob[(long)row * NP + col] = f2bf(fmaxf(acc[mi][ni][j], 0.f));
        }
      }
    }
  } else {
    unsigned short* ob = outB;           // qk [16384][256]
    #pragma unroll
    for (int mi = 0; mi < 4; ++mi) {
      #pragma unroll
      for (int ni = 0; ni < 4; ++ni) {
        int col  = n0 + wn + ni * 16 + fr;      // 0..255
        int rowb = m0 + wm + mi * 16 + kg * 4;
        float sc = (col < 128) ? weff[col >> 4] * 0.25f : 1.f;
        #pragma unroll
        for (int j = 0; j < 4; ++j) {
          int row = rowb + j;
          float v = acc[mi][ni][j];
          v = (v > 0.f) ? v : 0.01f * v;        // leaky_relu
          ob[(long)row * 256 + col] = f2bf(v * sc);
        }
      }
    }
  }
}

// ---------------- adj_bf = ln(A_pre)+skip (in place), t = bf16(ln(adj_bf)) zero-padded ----------------
__global__ void row_combine1(float* __restrict__ apre, const float* __restrict__ skip,
                             unsigned short* __restrict__ t) {
  int n = blockIdx.x, b = blockIdx.y, tid = threadIdx.x;
  long ro = (long)b * 1000000 + (long)n * N_;
  float* arow = apre + ro;
  const float* srow = skip + ro;
  float x[4]; float s = 0.f, s2 = 0.f;
  #pragma unroll
  for (int i = 0; i < 4; ++i) {
    int idx = tid + i * 256;
    x[i] = (idx < N_) ? arow[idx] : 0.f;
    s += x[i]; s2 += x[i] * x[i];
  }
  block_red2(s, s2);
  float mean = s * 1e-3f, var = s2 * 1e-3f - mean * mean;
  float r = rsqrtf(var + 1e-5f);
  float y[4]; s = 0.f; s2 = 0.f;
  #pragma unroll
  for (int i = 0; i < 4; ++i) {
    int idx = tid + i * 256;
    if (idx < N_) { y[i] = (x[i] - mean) * r + srow[idx]; arow[idx] = y[i]; }
    else y[i] = 0.f;
    s += y[i]; s2 += y[i] * y[i];
  }
  block_red2(s, s2);
  float mean2 = s * 1e-3f, var2 = s2 * 1e-3f - mean2 * mean2;
  float r2 = rsqrtf(var2 + 1e-5f);
  unsigned short* trow = t + ((long)b * NP + n) * NP;
  #pragma unroll
  for (int i = 0; i < 4; ++i) {
    int idx = tid + i * 256;                     // covers 0..1023
    float v = (idx < N_) ? (y[i] - mean2) * r2 : 0.f;
    trow[idx] = f2bf(v);
  }
}

// ---------------- final chain: ln(G2+adj_bf); +sgi; ln; relu; softmax -> in place on region0 ----------------
__global__ void row_final(float* __restrict__ g2, const float* __restrict__ adjbf,
                          const float* __restrict__ sgi) {
  int n = blockIdx.x, b = blockIdx.y, tid = threadIdx.x;
  long ro = (long)b * 1000000 + (long)n * N_;
  float* row = g2 + ro;
  const float* brow = adjbf + ro;
  const float* grow = sgi + (long)n * N_;
  float x[4]; float s = 0.f, s2 = 0.f;
  #pragma unroll
  for (int i = 0; i < 4; ++i) {
    int idx = tid + i * 256;
    x[i] = (idx < N_) ? (row[idx] + brow[idx]) : 0.f;
    s += x[i]; s2 += x[i] * x[i];
  }
  block_red2(s, s2);
  float m1 = s * 1e-3f, v1 = s2 * 1e-3f - m1 * m1, r1 = rsqrtf(v1 + 1e-5f);
  s = 0.f; s2 = 0.f;
  #pragma unroll
  for (int i = 0; i < 4; ++i) {
    int idx = tid + i * 256;
    x[i] = (idx < N_) ? ((x[i] - m1) * r1 + grow[idx]) : 0.f;
    s += x[i]; s2 += x[i] * x[i];
  }
  block_red2(s, s2);
  float m2 = s * 1e-3f, v2 = s2 * 1e-3f - m2 * m2, r2 = rsqrtf(v2 + 1e-5f);
  float mx = -1e30f;
  #pragma unroll
  for (int i = 0; i < 4; ++i) {
    int idx = tid + i * 256;
    if (idx < N_) { x[i] = fmaxf((x[i] - m2) * r2, 0.f); mx = fmaxf(mx, x[i]); }
  }
  block_redmax(mx);
  float es = 0.f, d = 0.f;
  #pragma unroll
  for (int i = 0; i < 4; ++i) {
    int idx = tid + i * 256;
    if (idx < N_) { x[i] = __expf(x[i] - mx); es += x[i]; } else x[i] = 0.f;
  }
  block_red2(es, d);
  float inv = 1.f / es;
  #pragma unroll
  for (int i = 0; i < 4; ++i) {
    int idx = tid + i * 256;
    if (idx < N_) row[idx] = x[i] * inv;
  }
}

// ---------------- adj_static broadcast to [B,N,N] ----------------
__global__ void broadcast_static(const float* __restrict__ adjs, float* __restrict__ out1) {
  long i = (long)blockIdx.x * 256 + threadIdx.x;   // over 250,000 float4
  if (i < 250000) {
    float4 v = ((const float4*)adjs)[i];
    #pragma unroll
    for (int b = 0; b < B_; ++b) ((float4*)out1)[(long)b * 250000 + i] = v;
  }
}

__global__ void copy_s(const float* __restrict__ src, float* __restrict__ dst) {
  int i = blockIdx.x * 256 + threadIdx.x;
  if (i < N_ * DN) dst[i] = src[i];
}

// ---------------- colsum + Frobenius of adj_static (segmented, atomic-accumulated) ----------------
__global__ void colsum_fnorm(const float* __restrict__ adjs, float* __restrict__ colsum,
                             float* __restrict__ fnorm) {
  int m = blockIdx.x * 256 + threadIdx.x;      // 0..1023
  int n0 = blockIdx.y * 63;                    // 16 segments x 63 rows >= 1000
  int ne = min(n0 + 63, N_);
  float c = 0.f, f = 0.f;
  if (m < N_) {
    for (int n = n0; n < ne; ++n) { float v = adjs[(long)n * N_ + m]; c += v; f += v * v; }
    atomicAdd(&colsum[m], c);
  }
  float d = 0.f; block_red2(f, d);
  if (threadIdx.x == 0) atomicAdd(fnorm, f);
}

// ---------------- trace term: tr[b] += sum_{m,d} (A^T X_b)[m,d] * X_b[m,d]  ----------------
// grid (16 m-tiles, 16 b, 4 n-segments); block 256 = 16x16 threads, 4x4 register tile.
__global__ __launch_bounds__(256)
void trace_kernel(const float* __restrict__ adjs, const float* __restrict__ x,
                  float* __restrict__ tr) {
  __shared__ float A_s[64 * 64];
  __shared__ float X_s[64 * 64];
  const int tid = threadIdx.x;
  const int tx = tid & 15, ty = tid >> 4;
  const int m0 = blockIdx.x * 64;
  const int b  = blockIdx.y;
  const int nseg = blockIdx.z;
  const float* xb = x + (long)b * (N_ * DN);

  float acc[4][4];
  #pragma unroll
  for (int i = 0; i < 4; ++i)
    #pragma unroll
    for (int j = 0; j < 4; ++j) acc[i][j] = 0.f;

  for (int cc = 0; cc < 4; ++cc) {
    int n0 = (nseg * 4 + cc) * 64;
    // stage A[n0+nn][m0+cm] and X[n0+nn][cm]; coalesced scalar loads, masked
    #pragma unroll
    for (int k = 0; k < 16; ++k) {
      int i = tid + k * 256;                 // 0..4095
      int nn = i >> 6, cm = i & 63;
      int n = n0 + nn;
      A_s[i] = (n < N_ && (m0 + cm) < N_) ? adjs[(long)n * N_ + m0 + cm] : 0.f;
      X_s[i] = (n < N_) ? xb[(long)n * DN + cm] : 0.f;
    }
    __syncthreads();
    #pragma unroll 8
    for (int nn = 0; nn < 64; ++nn) {
      float4 av = *(const float4*)&A_s[nn * 64 + ty * 4];   // m-direction
      float4 xv = *(const float4*)&X_s[nn * 64 + tx * 4];   // d-direction
      #pragma unroll
      for (int i = 0; i < 4; ++i) {
        float a = (&av.x)[i];
        acc[i][0] += a * xv.x;
        acc[i][1] += a * xv.y;
        acc[i][2] += a * xv.z;
        acc[i][3] += a * xv.w;
      }
    }
    __syncthreads();
  }

  // dot partial Y-tile with X[m][d]
  float v = 0.f;
  #pragma unroll
  for (int i = 0; i < 4; ++i) {
    int m = m0 + ty * 4 + i;
    if (m < N_) {
      float4 xm = *(const float4*)&xb[(long)m * DN + tx * 4];
      v += acc[i][0] * xm.x + acc[i][1] * xm.y + acc[i][2] * xm.z + acc[i][3] * xm.w;
    }
  }
  float d = 0.f; block_red2(v, d);
  if (tid == 0) atomicAdd(&tr[b], v);
}

// ---------------- gl_loss ----------------
__global__ void gl_final(const float* __restrict__ sq, const float* __restrict__ rowsum,
                         const float* __restrict__ colsum, const float* __restrict__ tr,
                         const float* __restrict__ fnorm, float* __restrict__ gl) {
  int b = blockIdx.x, tid = threadIdx.x;
  float s = 0.f;
  for (int i = tid; i < N_; i += 256) s += sq[(long)b * N_ + i] * (rowsum[i] + colsum[i]);
  float d = 0.f; block_red2(s, d);
  if (tid == 0) gl[b] = (s - 2.f * tr[b]) * 1e-3f + fnorm[0] * 1e-3f;
}

// ---------------- launch ----------------
extern "C" void kernel_launch(void* const* d_in, const int* in_sizes, int n_in,
                              void* d_out, int out_size, void* d_ws, size_t ws_size,
                              hipStream_t stream) {
  (void)in_sizes; (void)n_in; (void)out_size; (void)ws_size;
  const float* nodevec_fusion = (const float*)d_in[0];
  const float* nodevec_s      = (const float*)d_in[1];
  const float* node_input     = (const float*)d_in[2];
  const float* nodevec_dy     = (const float*)d_in[3];
  const float* w_q            = (const float*)d_in[4];
  const float* w_k            = (const float*)d_in[5];
  const float* node_w         = (const float*)d_in[6];
  const float* mlp_w          = (const float*)d_in[7];
  const float* mlp_b          = (const float*)d_in[8];
  const float* attn_linear    = (const float*)d_in[9];
  const float* attn_linear_1  = (const float*)d_in[10];

  float* out  = (float*)d_out;
  float* out0 = out;               // adj_dynamic [16,1000,1000]; doubles as GEMM2 scratch
  float* out1 = out + 16000000;    // adj_static_b; doubles as skip_atten scratch
  float* outS = out + 32000000;    // nodevec_s copy
  float* outGL = out + 32064000;   // gl_loss[16]

  char* wp = (char*)d_ws;
  auto alloc = [&](size_t bytes) { char* p = wp; wp += (bytes + 255) & ~(size_t)255; return p; };
  float* adjs            = (float*)alloc((size_t)N_ * N_ * 4);
  float* sgi             = (float*)alloc((size_t)N_ * N_ * 4);
  float* bufbf           = (float*)alloc((size_t)B_ * N_ * N_ * 4);     // A_pre -> adj_bf
  unsigned short* tbf    = (unsigned short*)alloc((size_t)B_ * NP * NP * 2);
  unsigned short* afbf   = (unsigned short*)alloc((size_t)B_ * NP * NP * 2);
  unsigned short* L1T    = (unsigned short*)alloc((size_t)NP * NP * 2);
  unsigned short* L2T    = (unsigned short*)alloc((size_t)NP * NP * 2);
  unsigned short* nv11   = (unsigned short*)alloc((size_t)B_ * NP * DN * 2);
  unsigned short* fbf    = (unsigned short*)alloc((size_t)B_ * NP * DN * 2);
  unsigned short* qk     = (unsigned short*)alloc((size_t)B_ * NP * 256 * 2);
  unsigned short* wt     = (unsigned short*)alloc((size_t)256 * DN * 2);
  float* sq              = (float*)alloc((size_t)B_ * N_ * 4);
  float* colsum          = (float*)alloc(4096);
  float* rowsum          = (float*)alloc(4096);
  float* weff            = (float*)alloc(256);
  float* tr              = (float*)alloc(256);
  float* fnorm           = (float*)alloc(256);

  prep_kernel<<<1, 1024, 0, stream>>>(mlp_w, mlp_b, w_q, w_k, weff, tr, fnorm, colsum, wt);
  transpose_pad<<<dim3(32, 32), dim3(32, 8), 0, stream>>>(attn_linear,   L1T);
  transpose_pad<<<dim3(32, 32), dim3(32, 8), 0, stream>>>(attn_linear_1, L2T);
  gram_kernel<<<dim3(63, 63), dim3(16, 16), 0, stream>>>(nodevec_s,  adjs);
  gram_kernel<<<dim3(63, 63), dim3(16, 16), 0, stream>>>(nodevec_dy, sgi);
  row_ln_sm<<<1000, 256, 0, stream>>>(adjs, rowsum);                       // adj_static
  row_ln<<<dim3(1000, 1), 256, 0, stream>>>(sgi, 0L);                      // static_graph_inf
  fusion_ln<<<256, 256, 0, stream>>>(nodevec_fusion, node_w, node_input, fbf, nv11, sq);
  // qk = leaky(f @ [w_q|w_k]) with weff*0.25 folded into q cols
  gemm_bt<2><<<dim3(128, 2, 1), 256, 0, stream>>>(fbf, 0L, DN,
                                                  wt, 0L, DN, DN,
                                                  (float*)nullptr, 0L, qk, 0L, weff);
  // skip_pre = nv11 · nv11^T  -> out1 (region1 scratch)
  gemm_bt<0><<<dim3(8, 8, 16), 256, 0, stream>>>(nv11, (long)NP * DN, DN,
                                                 nv11, (long)NP * DN, DN, DN,
                                                 out1, 1000000L, (unsigned short*)nullptr, 0L,
                                                 (const float*)nullptr);
  row_ln<<<dim3(1000, 16), 256, 0, stream>>>(out1, 1000000L);              // skip_atten
  // A_pre = q · k^T -> bufbf   (q = qk cols 0..127, k = qk cols 128..255)
  gemm_bt<0><<<dim3(8, 8, 16), 256, 0, stream>>>(qk, (long)NP * 256, 256,
                                                 qk + 128, (long)NP * 256, 256, D_,
                                                 bufbf, 1000000L, (unsigned short*)nullptr, 0L,
                                                 (const float*)nullptr);
  row_combine1<<<dim3(1000, 16), 256, 0, stream>>>(bufbf, out1, tbf);      // adj_bf + t
  // adj_af = relu(t @ L1) -> bf16
  gemm_bt<1><<<dim3(8, 8, 16), 256, 0, stream>>>(tbf, (long)NP * NP, NP,
                                                 L1T, 0L, NP, NP,
                                                 (float*)nullptr, 0L, afbf, (long)NP * NP,
                                                 (const float*)nullptr);
  // G2 = adj_af @ L2 -> region0 (f32)
  gemm_bt<0><<<dim3(8, 8, 16), 256, 0, stream>>>(afbf, (long)NP * NP, NP,
                                                 L2T, 0L, NP, NP,
                                                 out0, 1000000L, (unsigned short*)nullptr, 0L,
                                                 (const float*)nullptr);
  row_final<<<dim3(1000, 16), 256, 0, stream>>>(out0, bufbf, sgi);         // adj_dynamic
  broadcast_static<<<977, 256, 0, stream>>>(adjs, out1);                   // adj_static_b
  copy_s<<<250, 256, 0, stream>>>(nodevec_s, outS);
  colsum_fnorm<<<dim3(4, 16), 256, 0, stream>>>(adjs, colsum, fnorm);
  trace_kernel<<<dim3(16, 16, 4), 256, 0, stream>>>(adjs, node_input, tr);
  gl_final<<<16, 256, 0, stream>>>(sq, rowsum, colsum, tr, fnorm, outGL);
}

// Round 6
// 487.348 us; speedup vs baseline: 2.5789x; 1.1052x over previous
//
#include <hip/hip_runtime.h>

// Shapes (fixed by the problem)
#define B_  16
#define N_  1000
#define NP  1024      // padded N for bf16 GEMM operands
#define DN  64
#define D_  128

typedef __attribute__((ext_vector_type(8))) short  short8;
typedef __attribute__((ext_vector_type(4))) float  f32x4;
typedef __attribute__((ext_vector_type(4))) unsigned short ushort4v;

// ---------------- helpers ----------------
__device__ __forceinline__ unsigned short f2bf(float v) {
  union { float f; unsigned int u; } c; c.f = v;
  unsigned int u = c.u;
  unsigned int r = (u + 0x7fffu + ((u >> 16) & 1u)) >> 16;   // RNE
  return (unsigned short)r;
}
__device__ __forceinline__ float bf2f(unsigned short h) {
  union { unsigned int u; float f; } c; c.u = ((unsigned int)h) << 16; return c.f;
}

// block-wide reductions; all callers use blockDim.x == 256 (4 waves)
__device__ __forceinline__ void block_red2(float& a, float& b) {
  __shared__ float sb[8];
  __syncthreads();
  float ra = a, rb = b;
  #pragma unroll
  for (int o = 32; o > 0; o >>= 1) { ra += __shfl_down(ra, o); rb += __shfl_down(rb, o); }
  int w = threadIdx.x >> 6;
  if ((threadIdx.x & 63) == 0) { sb[w] = ra; sb[4 + w] = rb; }
  __syncthreads();
  a = sb[0] + sb[1] + sb[2] + sb[3];
  b = sb[4] + sb[5] + sb[6] + sb[7];
}

__device__ __forceinline__ void block_redmax(float& a) {
  __shared__ float sm[4];
  __syncthreads();
  float ra = a;
  #pragma unroll
  for (int o = 32; o > 0; o >>= 1) ra = fmaxf(ra, __shfl_down(ra, o));
  if ((threadIdx.x & 63) == 0) sm[threadIdx.x >> 6] = ra;
  __syncthreads();
  a = fmaxf(fmaxf(sm[0], sm[1]), fmaxf(sm[2], sm[3]));
}

// ---------------- tiny setup: w_eff, wt = [w_q^T ; w_k^T] bf16, zero tr/fnorm/colsum ----------------
__global__ void prep_kernel(const float* __restrict__ mlp_w, const float* __restrict__ mlp_b,
                            const float* __restrict__ w_q, const float* __restrict__ w_k,
                            float* __restrict__ weff, float* __restrict__ tr,
                            float* __restrict__ fnorm, float* __restrict__ colsum,
                            unsigned short* __restrict__ wt) {
  int t = threadIdx.x;   // 1024 threads
  if (t < 8) {
    float s = 1.f;                    // +1 from the residual branch of the 1x1 conv
    for (int o = 0; o < 8; ++o) s += mlp_w[o * 8 + t];
    weff[t] = s;
  }
  if (t < 16) tr[t] = 0.f;
  if (t == 16) fnorm[0] = 0.f;
  colsum[t] = 0.f;
  // wt[col][d] = w_q[d][col] (col<128) or w_k[d][col-128]
  for (int i = t; i < 256 * 64; i += 1024) {
    int col = i >> 6, d = i & 63;
    float v = (col < 128) ? w_q[d * D_ + col] : w_k[d * D_ + (col - 128)];
    wt[i] = f2bf(v);
  }
  (void)mlp_b;  // b_eff is added uniformly pre-LayerNorm -> shift-invariant -> no-op
}

// ---------------- transpose + cast + zero-pad: [1000x1000]f32 -> [1024x1024]bf16^T ----------------
__global__ void transpose_pad(const float* __restrict__ in, unsigned short* __restrict__ out) {
  __shared__ float tile[32][33];
  int bx = blockIdx.x * 32, by = blockIdx.y * 32;
  int tx = threadIdx.x, ty = threadIdx.y;      // (32,8)
  #pragma unroll
  for (int i = 0; i < 32; i += 8) {
    int r = by + ty + i, c = bx + tx;
    tile[ty + i][tx] = (r < N_ && c < N_) ? in[(long)r * N_ + c] : 0.f;
  }
  __syncthreads();
  #pragma unroll
  for (int i = 0; i < 32; i += 8) {
    int r = bx + ty + i, c = by + tx;          // out[r][c] = in[c][r]
    out[(long)r * NP + c] = f2bf(tile[tx][ty + i]);
  }
}

// ---------------- small gram: C[i,j] = X[i,:]·X[j,:], X [1000x64], row stride ldc ----------------
__global__ void gram_kernel(const float* __restrict__ X, float* __restrict__ C, int ldc) {
  __shared__ float Xi[16][65], Xj[16][65];
  int tx = threadIdx.x, ty = threadIdx.y;      // (16,16)
  int i0 = blockIdx.y * 16, j0 = blockIdx.x * 16;
  #pragma unroll
  for (int kk = 0; kk < 64; kk += 16) {
    int r = i0 + ty;  Xi[ty][kk + tx] = (r < N_) ? X[(long)r * DN + kk + tx] : 0.f;
    int rj = j0 + ty; Xj[ty][kk + tx] = (rj < N_) ? X[(long)rj * DN + kk + tx] : 0.f;
  }
  __syncthreads();
  float acc = 0.f;
  #pragma unroll
  for (int d = 0; d < 64; ++d) acc += Xi[ty][d] * Xj[tx][d];
  int i = i0 + ty, j = j0 + tx;
  if (i < N_ && j < N_) C[(long)i * ldc + j] = acc;
}

// ---------------- row LayerNorm (in place), rows of length 1000, row stride ld ----------------
__global__ void row_ln(float* __restrict__ base, int ld) {
  int tid = threadIdx.x;
  float* row = base + (long)blockIdx.x * ld;
  float x[4]; float s = 0.f, s2 = 0.f;
  #pragma unroll
  for (int i = 0; i < 4; ++i) {
    int idx = tid + i * 256;
    x[i] = (idx < N_) ? row[idx] : 0.f;
    s += x[i]; s2 += x[i] * x[i];
  }
  block_red2(s, s2);
  float mean = s * 1e-3f, var = s2 * 1e-3f - mean * mean;
  float r = rsqrtf(var + 1e-5f);
  #pragma unroll
  for (int i = 0; i < 4; ++i) {
    int idx = tid + i * 256;
    if (idx < N_) row[idx] = (x[i] - mean) * r;
  }
}

// ---------------- row LN -> relu -> softmax (adj_static), plus rowsum ----------------
__global__ void row_ln_sm(float* __restrict__ mat, float* __restrict__ rowsum) {
  int n = blockIdx.x, tid = threadIdx.x;
  float* row = mat + (long)n * N_;
  float x[4]; float s = 0.f, s2 = 0.f;
  #pragma unroll
  for (int i = 0; i < 4; ++i) {
    int idx = tid + i * 256;
    x[i] = (idx < N_) ? row[idx] : 0.f;
    s += x[i]; s2 += x[i] * x[i];
  }
  block_red2(s, s2);
  float mean = s * 1e-3f, var = s2 * 1e-3f - mean * mean;
  float r = rsqrtf(var + 1e-5f);
  float mx = -1e30f;
  #pragma unroll
  for (int i = 0; i < 4; ++i) {
    int idx = tid + i * 256;
    if (idx < N_) { x[i] = fmaxf((x[i] - mean) * r, 0.f); mx = fmaxf(mx, x[i]); }
  }
  block_redmax(mx);
  float es = 0.f, d = 0.f;
  #pragma unroll
  for (int i = 0; i < 4; ++i) {
    int idx = tid + i * 256;
    if (idx < N_) { x[i] = __expf(x[i] - mx); es += x[i]; } else x[i] = 0.f;
  }
  block_red2(es, d);
  float inv = 1.f / es; float ps = 0.f;
  #pragma unroll
  for (int i = 0; i < 4; ++i) {
    int idx = tid + i * 256;
    if (idx < N_) { x[i] *= inv; row[idx] = x[i]; ps += x[i]; }
  }
  d = 0.f; block_red2(ps, d);
  if (tid == 0) rowsum[n] = ps;
}

// ---------------- fusion LN (one wave per row), nv11, sq; zero-padded bf16 outputs ----------------
__global__ __launch_bounds__(256)
void fusion_ln(const float* __restrict__ fus, const float* __restrict__ node_w,
               const float* __restrict__ node_input,
               unsigned short* __restrict__ fbf, unsigned short* __restrict__ nv11,
               float* __restrict__ sq) {
  int wid = blockIdx.x * 4 + (threadIdx.x >> 6);   // 0..1023
  int lane = threadIdx.x & 63;
  #pragma unroll 1
  for (int r = 0; r < 16; ++r) {
    int row = wid * 16 + r;                        // padded row space [16384]
    int b = row >> 10, n = row & 1023;
    long po = (long)row * DN + lane;
    if (n < N_) {
      long io = ((long)b * N_ + n) * DN + lane;
      float xv = fus[io];
      float s = xv, s2 = xv * xv;
      #pragma unroll
      for (int o = 32; o > 0; o >>= 1) { s += __shfl_xor(s, o); s2 += __shfl_xor(s2, o); }
      float mean = s * (1.f / DN);
      float var  = s2 * (1.f / DN) - mean * mean;
      float fv = (xv - mean) * rsqrtf(var + 1e-5f);
      float rs = fv;
      #pragma unroll
      for (int o = 32; o > 0; o >>= 1) rs += __shfl_xor(rs, o);
      fbf[po]  = f2bf(fv);
      nv11[po] = f2bf(rs * node_w[(long)n * DN + lane] + fv);
      float xi = node_input[io];
      float q2 = xi * xi;
      #pragma unroll
      for (int o = 32; o > 0; o >>= 1) q2 += __shfl_xor(q2, o);
      if (lane == 0) sq[(long)b * N_ + n] = q2;
    } else {
      fbf[po] = 0; nv11[po] = 0;
    }
  }
}

// ---------------- batched bf16 MFMA GEMM: C[b] = X[b] · Y[b]^T (m97-style 128^2 tile) ----------------
#define GLOAD_LDS16(gp, lp) \
  __builtin_amdgcn_global_load_lds((const __attribute__((address_space(1))) void*)(gp), \
                                   (__attribute__((address_space(3))) void*)(lp), 16, 0, 0)

// EPI 1: relu -> bf16 full-tile store, stride 1024.
// EPI 2: q/k epilogue -> leaky_relu; q cols (<128) scaled by weff*0.25; bf16, row stride 256.
// EPI 3: plain bf16 full-tile store, stride 1024 (padded buffers, no bounds checks).
template<int EPI>
__global__ __launch_bounds__(256, 2)
void gemm_bt(const unsigned short* __restrict__ X, long xbs, int ldx,
             const unsigned short* __restrict__ Y, long ybs, int ldy,
             int K,
             unsigned short* __restrict__ outB, long obsB,
             const float* __restrict__ weff) {
  __shared__ __align__(16) short As[128 * 32];
  __shared__ __align__(16) short Bs[128 * 32];
  const int tid = threadIdx.x;
  const int b  = blockIdx.z;
  const int m0 = blockIdx.x * 128;
  const int n0 = blockIdx.y * 128;
  const unsigned short* Xb = X + (long)b * xbs + (long)m0 * ldx;
  const unsigned short* Yb = Y + (long)b * ybs + (long)n0 * ldy;

  const int lane = tid & 63, w = tid >> 6;
  const int wm = (w >> 1) * 64, wn = (w & 1) * 64;   // 2x2 waves -> 64x64 each
  const int fr = lane & 15, kg = lane >> 4;

  // staging map: thread -> (row sr, k-slot ks); source column XOR-swizzled so that
  // LDS[row][slot] = X[row][(slot ^ p_row)*8 ..], p_row = (row>>1)&3  (rule 21: same involution on read)
  const int sr = tid >> 2;
  const int ks = tid & 3;
  const int c1 = ((ks ^ ((sr >> 1) & 3)) * 8);
  const int c2 = ((ks ^ (((sr + 64) >> 1) & 3)) * 8);

  f32x4 acc[4][4];
  #pragma unroll
  for (int mi = 0; mi < 4; ++mi)
    #pragma unroll
    for (int ni = 0; ni < 4; ++ni)
      acc[mi][ni] = (f32x4){0.f, 0.f, 0.f, 0.f};

  const short* Asp = (const short*)As;
  const short* Bsp = (const short*)Bs;

  for (int k0 = 0; k0 < K; k0 += 32) {
    GLOAD_LDS16(Xb + (long)sr * ldx + k0 + c1,        (char*)As + tid * 16);
    GLOAD_LDS16(Xb + (long)(sr + 64) * ldx + k0 + c2, (char*)As + 4096 + tid * 16);
    GLOAD_LDS16(Yb + (long)sr * ldy + k0 + c1,        (char*)Bs + tid * 16);
    GLOAD_LDS16(Yb + (long)(sr + 64) * ldy + k0 + c2, (char*)Bs + 4096 + tid * 16);
    __syncthreads();   // compiler emits s_waitcnt vmcnt(0) before s_barrier -> LDS valid
    short8 av[4], bv[4];
    #pragma unroll
    for (int mi = 0; mi < 4; ++mi) {
      int r = wm + mi * 16 + fr;
      av[mi] = *(const short8*)&Asp[r * 32 + ((kg ^ ((r >> 1) & 3)) * 8)];
    }
    #pragma unroll
    for (int ni = 0; ni < 4; ++ni) {
      int r = wn + ni * 16 + fr;
      bv[ni] = *(const short8*)&Bsp[r * 32 + ((kg ^ ((r >> 1) & 3)) * 8)];
    }
    #pragma unroll
    for (int mi = 0; mi < 4; ++mi)
      #pragma unroll
      for (int ni = 0; ni < 4; ++ni)
        acc[mi][ni] = __builtin_amdgcn_mfma_f32_16x16x32_bf16(av[mi], bv[ni], acc[mi][ni], 0, 0, 0);
    __syncthreads();   // protect LDS from next-iter staging
  }

  // C/D layout (m89-verified): col = lane&15, row = (lane>>4)*4 + reg
  if (EPI == 1) {
    unsigned short* ob = outB + (long)b * obsB;
    #pragma unroll
    for (int mi = 0; mi < 4; ++mi) {
      #pragma unroll
      for (int ni = 0; ni < 4; ++ni) {
        int col  = n0 + wn + ni * 16 + fr;
        int rowb = m0 + wm + mi * 16 + kg * 4;
        #pragma unroll
        for (int j = 0; j < 4; ++j)
          ob[(long)(rowb + j) * NP + col] = f2bf(fmaxf(acc[mi][ni][j], 0.f));
      }
    }
  } else if (EPI == 2) {
    unsigned short* ob = outB;           // qk [16384][256]
    #pragma unroll
    for (int mi = 0; mi < 4; ++mi) {
      #pragma unroll
      for (int ni = 0; ni < 4; ++ni) {
        int col  = n0 + wn + ni * 16 + fr;      // 0..255
        int rowb = m0 + wm + mi * 16 + kg * 4;
        float sc = (col < 128) ? weff[col >> 4] * 0.25f : 1.f;
        #pragma unroll
        for (int j = 0; j < 4; ++j) {
          float v = acc[mi][ni][j];
          v = (v > 0.f) ? v : 0.01f * v;        // leaky_relu
          ob[(long)(rowb + j) * 256 + col] = f2bf(v * sc);
        }
      }
    }
  } else {
    unsigned short* ob = outB + (long)b * obsB;
    #pragma unroll
    for (int mi = 0; mi < 4; ++mi) {
      #pragma unroll
      for (int ni = 0; ni < 4; ++ni) {
        int col  = n0 + wn + ni * 16 + fr;
        int rowb = m0 + wm + mi * 16 + kg * 4;
        #pragma unroll
        for (int j = 0; j < 4; ++j)
          ob[(long)(rowb + j) * NP + col] = f2bf(acc[mi][ni][j]);
      }
    }
  }
}

// ---------------- adj_bf = ln(apre)+ln(skip); t = bf16(ln(adj_bf)); all bf16, stride 1024 ----------------
__global__ __launch_bounds__(256)
void row_combine1(const unsigned short* __restrict__ apre, const unsigned short* __restrict__ skip,
                  unsigned short* __restrict__ adjbf, unsigned short* __restrict__ tbf) {
  int n = blockIdx.x, b = blockIdx.y, tid = threadIdx.x;
  long ro = ((long)b * NP + n) * NP + tid * 4;
  ushort4v a4 = *(const ushort4v*)(apre + ro);
  ushort4v s4 = *(const ushort4v*)(skip + ro);
  float xa[4], xs[4];
  float sa = 0.f, sa2 = 0.f, ss = 0.f, ss2 = 0.f;
  #pragma unroll
  for (int j = 0; j < 4; ++j) {
    bool mm = (tid * 4 + j) < N_;
    xa[j] = mm ? bf2f(a4[j]) : 0.f;
    xs[j] = mm ? bf2f(s4[j]) : 0.f;
    sa += xa[j]; sa2 += xa[j] * xa[j];
    ss += xs[j]; ss2 += xs[j] * xs[j];
  }
  block_red2(sa, sa2);
  block_red2(ss, ss2);
  float ma = sa * 1e-3f, ra = rsqrtf(sa2 * 1e-3f - ma * ma + 1e-5f);
  float ms = ss * 1e-3f, rs = rsqrtf(ss2 * 1e-3f - ms * ms + 1e-5f);
  float y[4]; float sy = 0.f, sy2 = 0.f;
  #pragma unroll
  for (int j = 0; j < 4; ++j) {
    y[j] = ((tid * 4 + j) < N_) ? (xa[j] - ma) * ra + (xs[j] - ms) * rs : 0.f;
    sy += y[j]; sy2 += y[j] * y[j];
  }
  block_red2(sy, sy2);
  float my = sy * 1e-3f, ry = rsqrtf(sy2 * 1e-3f - my * my + 1e-5f);
  ushort4v o1, o2;
  #pragma unroll
  for (int j = 0; j < 4; ++j) {
    o1[j] = f2bf(y[j]);
    o2[j] = ((tid * 4 + j) < N_) ? f2bf((y[j] - my) * ry) : (unsigned short)0;
  }
  *(ushort4v*)(adjbf + ro) = o1;
  *(ushort4v*)(tbf + ro) = o2;
}

// ---------------- final chain: ln(G2+adj_bf); +sgi; ln; relu; softmax -> f32 out ----------------
__global__ __launch_bounds__(256)
void row_final(const unsigned short* __restrict__ g2, const unsigned short* __restrict__ adjbf,
               const float* __restrict__ sgi, float* __restrict__ outp) {
  int n = blockIdx.x, b = blockIdx.y, tid = threadIdx.x;
  long ro = ((long)b * NP + n) * NP + tid * 4;
  ushort4v g4 = *(const ushort4v*)(g2 + ro);
  ushort4v a4 = *(const ushort4v*)(adjbf + ro);
  float4 gr = *(const float4*)(sgi + (long)n * NP + tid * 4);
  const float* grp = (const float*)&gr;
  float x[4]; float s = 0.f, s2 = 0.f;
  #pragma unroll
  for (int j = 0; j < 4; ++j) {
    x[j] = ((tid * 4 + j) < N_) ? bf2f(g4[j]) + bf2f(a4[j]) : 0.f;
    s += x[j]; s2 += x[j] * x[j];
  }
  block_red2(s, s2);
  float m1 = s * 1e-3f, r1 = rsqrtf(s2 * 1e-3f - m1 * m1 + 1e-5f);
  s = 0.f; s2 = 0.f;
  #pragma unroll
  for (int j = 0; j < 4; ++j) {
    x[j] = ((tid * 4 + j) < N_) ? (x[j] - m1) * r1 + grp[j] : 0.f;
    s += x[j]; s2 += x[j] * x[j];
  }
  block_red2(s, s2);
  float m2 = s * 1e-3f, r2 = rsqrtf(s2 * 1e-3f - m2 * m2 + 1e-5f);
  float mx = -1e30f;
  #pragma unroll
  for (int j = 0; j < 4; ++j) {
    if ((tid * 4 + j) < N_) { x[j] = fmaxf((x[j] - m2) * r2, 0.f); mx = fmaxf(mx, x[j]); }
  }
  block_redmax(mx);
  float es = 0.f, dd = 0.f;
  #pragma unroll
  for (int j = 0; j < 4; ++j) {
    if ((tid * 4 + j) < N_) { x[j] = __expf(x[j] - mx); es += x[j]; } else x[j] = 0.f;
  }
  block_red2(es, dd);
  float inv = 1.f / es;
  if (tid < 250) {   // rows are 16B-aligned (1000 % 4 == 0) -> clean float4 stores
    float4 o = make_float4(x[0] * inv, x[1] * inv, x[2] * inv, x[3] * inv);
    *(float4*)(outp + (long)b * 1000000 + (long)n * N_ + tid * 4) = o;
  }
}

// ---------------- adj_static broadcast to [B,N,N] ----------------
__global__ void broadcast_static(const float* __restrict__ adjs, float* __restrict__ out1) {
  long i = (long)blockIdx.x * 256 + threadIdx.x;   // over 250,000 float4
  if (i < 250000) {
    float4 v = ((const float4*)adjs)[i];
    #pragma unroll
    for (int b = 0; b < B_; ++b) ((float4*)out1)[(long)b * 250000 + i] = v;
  }
}

__global__ void copy_s(const float* __restrict__ src, float* __restrict__ dst) {
  int i = blockIdx.x * 256 + threadIdx.x;
  if (i < N_ * DN) dst[i] = src[i];
}

// ---------------- colsum + Frobenius of adj_static (segmented, atomic-accumulated) ----------------
__global__ void colsum_fnorm(const float* __restrict__ adjs, float* __restrict__ colsum,
                             float* __restrict__ fnorm) {
  int m = blockIdx.x * 256 + threadIdx.x;      // 0..1023
  int n0 = blockIdx.y * 63;                    // 16 segments x 63 rows >= 1000
  int ne = min(n0 + 63, N_);
  float c = 0.f, f = 0.f;
  if (m < N_) {
    for (int n = n0; n < ne; ++n) { float v = adjs[(long)n * N_ + m]; c += v; f += v * v; }
    atomicAdd(&colsum[m], c);
  }
  float d = 0.f; block_red2(f, d);
  if (threadIdx.x == 0) atomicAdd(fnorm, f);
}

// ---------------- trace term: tr[b] += sum_{m,d} (A^T X_b)[m,d] * X_b[m,d]  ----------------
__global__ __launch_bounds__(256)
void trace_kernel(const float* __restrict__ adjs, const float* __restrict__ x,
                  float* __restrict__ tr) {
  __shared__ float A_s[64 * 64];
  __shared__ float X_s[64 * 64];
  const int tid = threadIdx.x;
  const int tx = tid & 15, ty = tid >> 4;
  const int m0 = blockIdx.x * 64;
  const int b  = blockIdx.y;
  const int nseg = blockIdx.z;
  const float* xb = x + (long)b * (N_ * DN);

  float acc[4][4];
  #pragma unroll
  for (int i = 0; i < 4; ++i)
    #pragma unroll
    for (int j = 0; j < 4; ++j) acc[i][j] = 0.f;

  for (int cc = 0; cc < 4; ++cc) {
    int n0 = (nseg * 4 + cc) * 64;
    #pragma unroll
    for (int k = 0; k < 16; ++k) {
      int i = tid + k * 256;                 // 0..4095
      int nn = i >> 6, cm = i & 63;
      int n = n0 + nn;
      A_s[i] = (n < N_ && (m0 + cm) < N_) ? adjs[(long)n * N_ + m0 + cm] : 0.f;
      X_s[i] = (n < N_) ? xb[(long)n * DN + cm] : 0.f;
    }
    __syncthreads();
    #pragma unroll 8
    for (int nn = 0; nn < 64; ++nn) {
      float4 av = *(const float4*)&A_s[nn * 64 + ty * 4];   // m-direction
      float4 xv = *(const float4*)&X_s[nn * 64 + tx * 4];   // d-direction
      #pragma unroll
      for (int i = 0; i < 4; ++i) {
        float a = (&av.x)[i];
        acc[i][0] += a * xv.x;
        acc[i][1] += a * xv.y;
        acc[i][2] += a * xv.z;
        acc[i][3] += a * xv.w;
      }
    }
    __syncthreads();
  }

  float v = 0.f;
  #pragma unroll
  for (int i = 0; i < 4; ++i) {
    int m = m0 + ty * 4 + i;
    if (m < N_) {
      float4 xm = *(const float4*)&xb[(long)m * DN + tx * 4];
      v += acc[i][0] * xm.x + acc[i][1] * xm.y + acc[i][2] * xm.z + acc[i][3] * xm.w;
    }
  }
  float d = 0.f; block_red2(v, d);
  if (tid == 0) atomicAdd(&tr[b], v);
}

// ---------------- gl_loss ----------------
__global__ void gl_final(const float* __restrict__ sq, const float* __restrict__ rowsum,
                         const float* __restrict__ colsum, const float* __restrict__ tr,
                         const float* __restrict__ fnorm, float* __restrict__ gl) {
  int b = blockIdx.x, tid = threadIdx.x;
  float s = 0.f;
  for (int i = tid; i < N_; i += 256) s += sq[(long)b * N_ + i] * (rowsum[i] + colsum[i]);
  float d = 0.f; block_red2(s, d);
  if (tid == 0) gl[b] = (s - 2.f * tr[b]) * 1e-3f + fnorm[0] * 1e-3f;
}

// ---------------- launch ----------------
extern "C" void kernel_launch(void* const* d_in, const int* in_sizes, int n_in,
                              void* d_out, int out_size, void* d_ws, size_t ws_size,
                              hipStream_t stream) {
  (void)in_sizes; (void)n_in; (void)out_size; (void)ws_size;
  const float* nodevec_fusion = (const float*)d_in[0];
  const float* nodevec_s      = (const float*)d_in[1];
  const float* node_input     = (const float*)d_in[2];
  const float* nodevec_dy     = (const float*)d_in[3];
  const float* w_q            = (const float*)d_in[4];
  const float* w_k            = (const float*)d_in[5];
  const float* node_w         = (const float*)d_in[6];
  const float* mlp_w          = (const float*)d_in[7];
  const float* mlp_b          = (const float*)d_in[8];
  const float* attn_linear    = (const float*)d_in[9];
  const float* attn_linear_1  = (const float*)d_in[10];

  float* out  = (float*)d_out;
  float* out0 = out;               // adj_dynamic [16,1000,1000]
  float* out1 = out + 16000000;    // adj_static_b
  float* outS = out + 32000000;    // nodevec_s copy
  float* outGL = out + 32064000;   // gl_loss[16]

  char* wp = (char*)d_ws;
  auto alloc = [&](size_t bytes) { char* p = wp; wp += (bytes + 255) & ~(size_t)255; return p; };
  float* adjs            = (float*)alloc((size_t)N_ * N_ * 4);
  float* sgi             = (float*)alloc((size_t)NP * NP * 4);            // stride 1024
  unsigned short* apre   = (unsigned short*)alloc((size_t)B_ * NP * NP * 2);  // A_pre, reused as G2
  unsigned short* skipb  = (unsigned short*)alloc((size_t)B_ * NP * NP * 2);  // skip_pre
  unsigned short* adjbf  = (unsigned short*)alloc((size_t)B_ * NP * NP * 2);  // adj_bf
  unsigned short* tbf    = (unsigned short*)alloc((size_t)B_ * NP * NP * 2);
  unsigned short* afbf   = (unsigned short*)alloc((size_t)B_ * NP * NP * 2);
  unsigned short* L1T    = (unsigned short*)alloc((size_t)NP * NP * 2);
  unsigned short* L2T    = (unsigned short*)alloc((size_t)NP * NP * 2);
  unsigned short* nv11   = (unsigned short*)alloc((size_t)B_ * NP * DN * 2);
  unsigned short* fbf    = (unsigned short*)alloc((size_t)B_ * NP * DN * 2);
  unsigned short* qk     = (unsigned short*)alloc((size_t)B_ * NP * 256 * 2);
  unsigned short* wt     = (unsigned short*)alloc((size_t)256 * DN * 2);
  float* sq              = (float*)alloc((size_t)B_ * N_ * 4);
  float* colsum          = (float*)alloc(4096);
  float* rowsum          = (float*)alloc(4096);
  float* weff            = (float*)alloc(256);
  float* tr              = (float*)alloc(256);
  float* fnorm           = (float*)alloc(256);

  prep_kernel<<<1, 1024, 0, stream>>>(mlp_w, mlp_b, w_q, w_k, weff, tr, fnorm, colsum, wt);
  transpose_pad<<<dim3(32, 32), dim3(32, 8), 0, stream>>>(attn_linear,   L1T);
  transpose_pad<<<dim3(32, 32), dim3(32, 8), 0, stream>>>(attn_linear_1, L2T);
  gram_kernel<<<dim3(63, 63), dim3(16, 16), 0, stream>>>(nodevec_s,  adjs, N_);
  gram_kernel<<<dim3(63, 63), dim3(16, 16), 0, stream>>>(nodevec_dy, sgi, NP);
  row_ln_sm<<<1000, 256, 0, stream>>>(adjs, rowsum);                       // adj_static
  row_ln<<<1000, 256, 0, stream>>>(sgi, NP);                               // static_graph_inf
  fusion_ln<<<256, 256, 0, stream>>>(nodevec_fusion, node_w, node_input, fbf, nv11, sq);
  // qk = leaky(f @ [w_q|w_k]) with weff*0.25 folded into q cols
  gemm_bt<2><<<dim3(128, 2, 1), 256, 0, stream>>>(fbf, 0L, DN,
                                                  wt, 0L, DN, DN,
                                                  qk, 0L, weff);
  // skip_pre = nv11 · nv11^T -> bf16
  gemm_bt<3><<<dim3(8, 8, 16), 256, 0, stream>>>(nv11, (long)NP * DN, DN,
                                                 nv11, (long)NP * DN, DN, DN,
                                                 skipb, (long)NP * NP, (const float*)nullptr);
  // A_pre = q · k^T -> bf16   (q = qk cols 0..127, k = qk cols 128..255)
  gemm_bt<3><<<dim3(8, 8, 16), 256, 0, stream>>>(qk, (long)NP * 256, 256,
                                                 qk + 128, (long)NP * 256, 256, D_,
                                                 apre, (long)NP * NP, (const float*)nullptr);
  // adj_bf = ln(A_pre) + ln(skip_pre); t = bf16(ln(adj_bf))
  row_combine1<<<dim3(1000, 16), 256, 0, stream>>>(apre, skipb, adjbf, tbf);
  // adj_af = relu(t @ L1) -> bf16
  gemm_bt<1><<<dim3(8, 8, 16), 256, 0, stream>>>(tbf, (long)NP * NP, NP,
                                                 L1T, 0L, NP, NP,
                                                 afbf, (long)NP * NP, (const float*)nullptr);
  // G2 = adj_af @ L2 -> bf16 (reuse apre buffer)
  gemm_bt<3><<<dim3(8, 8, 16), 256, 0, stream>>>(afbf, (long)NP * NP, NP,
                                                 L2T, 0L, NP, NP,
                                                 apre, (long)NP * NP, (const float*)nullptr);
  row_final<<<dim3(1000, 16), 256, 0, stream>>>(apre, adjbf, sgi, out0);   // adj_dynamic
  broadcast_static<<<977, 256, 0, stream>>>(adjs, out1);                   // adj_static_b
  copy_s<<<250, 256, 0, stream>>>(nodevec_s, outS);
  colsum_fnorm<<<dim3(4, 16), 256, 0, stream>>>(adjs, colsum, fnorm);
  trace_kernel<<<dim3(16, 16, 4), 256, 0, stream>>>(adjs, node_input, tr);
  gl_final<<<16, 256, 0, stream>>>(sq, rowsum, colsum, tr, fnorm, outGL);
}

// Round 11
// 471.806 us; speedup vs baseline: 2.6639x; 1.0329x over previous
//
#include <hip/hip_runtime.h>

// Shapes (fixed by the problem)
#define B_  16
#define N_  1000
#define NP  1024      // padded N for bf16 GEMM operands
#define DN  64
#define D_  128

typedef __attribute__((ext_vector_type(8))) short  short8;
typedef __attribute__((ext_vector_type(4))) float  f32x4;
typedef __attribute__((ext_vector_type(8))) unsigned short ushort8v;

// ---------------- helpers ----------------
__device__ __forceinline__ unsigned short f2bf(float v) {
  union { float f; unsigned int u; } c; c.f = v;
  unsigned int u = c.u;
  unsigned int r = (u + 0x7fffu + ((u >> 16) & 1u)) >> 16;   // RNE
  return (unsigned short)r;
}
__device__ __forceinline__ float bf2f(unsigned short h) {
  union { unsigned int u; float f; } c; c.u = ((unsigned int)h) << 16; return c.f;
}

__device__ __forceinline__ float wred(float v) {
  #pragma unroll
  for (int o = 32; o > 0; o >>= 1) v += __shfl_xor(v, o);
  return v;
}
__device__ __forceinline__ float wredmax(float v) {
  #pragma unroll
  for (int o = 32; o > 0; o >>= 1) v = fmaxf(v, __shfl_xor(v, o));
  return v;
}

// block-wide reduction (gl_final / trace / colsum only)
__device__ __forceinline__ void block_red2(float& a, float& b) {
  __shared__ float sb[8];
  __syncthreads();
  float ra = a, rb = b;
  #pragma unroll
  for (int o = 32; o > 0; o >>= 1) { ra += __shfl_down(ra, o); rb += __shfl_down(rb, o); }
  int w = threadIdx.x >> 6;
  if ((threadIdx.x & 63) == 0) { sb[w] = ra; sb[4 + w] = rb; }
  __syncthreads();
  a = sb[0] + sb[1] + sb[2] + sb[3];
  b = sb[4] + sb[5] + sb[6] + sb[7];
}

// ---------------- tiny setup: w_eff, wt = [w_q^T ; w_k^T] bf16, zero tr/fnorm/colsum ----------------
__global__ void prep_kernel(const float* __restrict__ mlp_w, const float* __restrict__ mlp_b,
                            const float* __restrict__ w_q, const float* __restrict__ w_k,
                            float* __restrict__ weff, float* __restrict__ tr,
                            float* __restrict__ fnorm, float* __restrict__ colsum,
                            unsigned short* __restrict__ wt) {
  int t = threadIdx.x;   // 1024 threads
  if (t < 8) {
    float s = 1.f;                    // +1 from the residual branch of the 1x1 conv
    for (int o = 0; o < 8; ++o) s += mlp_w[o * 8 + t];
    weff[t] = s;
  }
  if (t < 16) tr[t] = 0.f;
  if (t == 16) fnorm[0] = 0.f;
  colsum[t] = 0.f;
  // wt[col][d] = w_q[d][col] (col<128) or w_k[d][col-128]
  for (int i = t; i < 256 * 64; i += 1024) {
    int col = i >> 6, d = i & 63;
    float v = (col < 128) ? w_q[d * D_ + col] : w_k[d * D_ + (col - 128)];
    wt[i] = f2bf(v);
  }
  (void)mlp_b;  // b_eff is added uniformly pre-LayerNorm -> shift-invariant -> no-op
}

// ---------------- transpose + cast + zero-pad: [1000x1000]f32 -> [1024x1024]bf16^T ----------------
__global__ void transpose_pad(const float* __restrict__ in, unsigned short* __restrict__ out) {
  __shared__ float tile[32][33];
  int bx = blockIdx.x * 32, by = blockIdx.y * 32;
  int tx = threadIdx.x, ty = threadIdx.y;      // (32,8)
  #pragma unroll
  for (int i = 0; i < 32; i += 8) {
    int r = by + ty + i, c = bx + tx;
    tile[ty + i][tx] = (r < N_ && c < N_) ? in[(long)r * N_ + c] : 0.f;
  }
  __syncthreads();
  #pragma unroll
  for (int i = 0; i < 32; i += 8) {
    int r = bx + ty + i, c = by + tx;          // out[r][c] = in[c][r]
    out[(long)r * NP + c] = f2bf(tile[tx][ty + i]);
  }
}

// ---------------- gram: C[i,j] = X[i,:]·X[j,:]; 64x64 tile/block, 4x4 reg tile ----------------
__global__ __launch_bounds__(256)
void gram_kernel(const float* __restrict__ X, float* __restrict__ C, int ldc) {
  __shared__ float Xi[64 * 67];
  __shared__ float Xj[64 * 67];
  const int tid = threadIdx.x;
  const int tx = tid & 15, ty = tid >> 4;
  const int i0 = blockIdx.y * 64, j0 = blockIdx.x * 64;
  #pragma unroll
  for (int t = 0; t < 16; ++t) {
    int e = tid + t * 256;                 // 0..4095
    int r = e >> 6, c = e & 63;
    int ri = i0 + r, rj = j0 + r;
    Xi[r * 67 + c] = (ri < N_) ? X[(long)ri * DN + c] : 0.f;
    Xj[r * 67 + c] = (rj < N_) ? X[(long)rj * DN + c] : 0.f;
  }
  __syncthreads();
  float acc[4][4];
  #pragma unroll
  for (int i = 0; i < 4; ++i)
    #pragma unroll
    for (int j = 0; j < 4; ++j) acc[i][j] = 0.f;
  #pragma unroll 4
  for (int d = 0; d < 64; ++d) {
    float av[4], bv[4];
    #pragma unroll
    for (int i = 0; i < 4; ++i) av[i] = Xi[(ty * 4 + i) * 67 + d];
    #pragma unroll
    for (int j = 0; j < 4; ++j) bv[j] = Xj[(tx * 4 + j) * 67 + d];
    #pragma unroll
    for (int i = 0; i < 4; ++i)
      #pragma unroll
      for (int j = 0; j < 4; ++j) acc[i][j] += av[i] * bv[j];
  }
  int cc = j0 + tx * 4;
  #pragma unroll
  for (int i = 0; i < 4; ++i) {
    int r = i0 + ty * 4 + i;
    if (r < N_ && cc < N_) {               // 1000 % 4 == 0 -> full-float4 masking valid
      float4 o = make_float4(acc[i][0], acc[i][1], acc[i][2], acc[i][3]);
      *(float4*)&C[(long)r * ldc + cc] = o;
    }
  }
}

// ---------------- row LayerNorm (wave-per-row, in place), stride ld ----------------
__global__ __launch_bounds__(256)
void row_ln(float* __restrict__ base, int ld) {
  int w = threadIdx.x >> 6, lane = threadIdx.x & 63;
  int n = blockIdx.x * 4 + w;
  float* row = base + (long)n * ld;
  float x[16]; float s = 0.f, s2 = 0.f;
  #pragma unroll
  for (int c = 0; c < 2; ++c) {
    int bse = c * 512 + lane * 8;
    if (bse < N_) {
      float4 v0 = *(const float4*)(row + bse);
      float4 v1 = *(const float4*)(row + bse + 4);
      x[c*8+0]=v0.x; x[c*8+1]=v0.y; x[c*8+2]=v0.z; x[c*8+3]=v0.w;
      x[c*8+4]=v1.x; x[c*8+5]=v1.y; x[c*8+6]=v1.z; x[c*8+7]=v1.w;
    } else {
      #pragma unroll
      for (int j = 0; j < 8; ++j) x[c*8+j] = 0.f;
    }
    #pragma unroll
    for (int j = 0; j < 8; ++j) { s += x[c*8+j]; s2 += x[c*8+j]*x[c*8+j]; }
  }
  s = wred(s); s2 = wred(s2);
  float mean = s * 1e-3f, r = rsqrtf(s2 * 1e-3f - mean * mean + 1e-5f);
  #pragma unroll
  for (int c = 0; c < 2; ++c) {
    int bse = c * 512 + lane * 8;
    if (bse < N_) {
      float4 o0 = make_float4((x[c*8+0]-mean)*r, (x[c*8+1]-mean)*r, (x[c*8+2]-mean)*r, (x[c*8+3]-mean)*r);
      float4 o1 = make_float4((x[c*8+4]-mean)*r, (x[c*8+5]-mean)*r, (x[c*8+6]-mean)*r, (x[c*8+7]-mean)*r);
      *(float4*)(row + bse) = o0;
      *(float4*)(row + bse + 4) = o1;
    }
  }
}

// ---------------- row LN -> relu -> softmax (adj_static, wave-per-row), plus rowsum ----------------
__global__ __launch_bounds__(256)
void row_ln_sm(float* __restrict__ mat, float* __restrict__ rowsum) {
  int w = threadIdx.x >> 6, lane = threadIdx.x & 63;
  int n = blockIdx.x * 4 + w;
  float* row = mat + (long)n * N_;
  float x[16]; float s = 0.f, s2 = 0.f;
  #pragma unroll
  for (int c = 0; c < 2; ++c) {
    int bse = c * 512 + lane * 8;
    if (bse < N_) {
      float4 v0 = *(const float4*)(row + bse);
      float4 v1 = *(const float4*)(row + bse + 4);
      x[c*8+0]=v0.x; x[c*8+1]=v0.y; x[c*8+2]=v0.z; x[c*8+3]=v0.w;
      x[c*8+4]=v1.x; x[c*8+5]=v1.y; x[c*8+6]=v1.z; x[c*8+7]=v1.w;
    } else {
      #pragma unroll
      for (int j = 0; j < 8; ++j) x[c*8+j] = 0.f;
    }
    #pragma unroll
    for (int j = 0; j < 8; ++j) { s += x[c*8+j]; s2 += x[c*8+j]*x[c*8+j]; }
  }
  s = wred(s); s2 = wred(s2);
  float mean = s * 1e-3f, r = rsqrtf(s2 * 1e-3f - mean * mean + 1e-5f);
  float mx = -1e30f;
  #pragma unroll
  for (int c = 0; c < 2; ++c) {
    int bse = c * 512 + lane * 8;
    #pragma unroll
    for (int j = 0; j < 8; ++j) {
      if (bse < N_) { x[c*8+j] = fmaxf((x[c*8+j]-mean)*r, 0.f); mx = fmaxf(mx, x[c*8+j]); }
    }
  }
  mx = wredmax(mx);
  float es = 0.f;
  #pragma unroll
  for (int c = 0; c < 2; ++c) {
    int bse = c * 512 + lane * 8;
    #pragma unroll
    for (int j = 0; j < 8; ++j) {
      if (bse < N_) { x[c*8+j] = __expf(x[c*8+j] - mx); es += x[c*8+j]; } else x[c*8+j] = 0.f;
    }
  }
  es = wred(es);
  float inv = 1.f / es; float ps = 0.f;
  #pragma unroll
  for (int c = 0; c < 2; ++c) {
    int bse = c * 512 + lane * 8;
    #pragma unroll
    for (int j = 0; j < 8; ++j) { x[c*8+j] *= inv; ps += x[c*8+j]; }
    if (bse < N_) {
      float4 o0 = make_float4(x[c*8+0], x[c*8+1], x[c*8+2], x[c*8+3]);
      float4 o1 = make_float4(x[c*8+4], x[c*8+5], x[c*8+6], x[c*8+7]);
      *(float4*)(row + bse) = o0;
      *(float4*)(row + bse + 4) = o1;
    }
  }
  ps = wred(ps);
  if (lane == 0) rowsum[n] = ps;
}

// ---------------- fusion LN (one wave per row), nv11, sq; zero-padded bf16 outputs ----------------
__global__ __launch_bounds__(256)
void fusion_ln(const float* __restrict__ fus, const float* __restrict__ node_w,
               const float* __restrict__ node_input,
               unsigned short* __restrict__ fbf, unsigned short* __restrict__ nv11,
               float* __restrict__ sq) {
  int wid = blockIdx.x * 4 + (threadIdx.x >> 6);   // 0..1023
  int lane = threadIdx.x & 63;
  #pragma unroll 1
  for (int r = 0; r < 16; ++r) {
    int row = wid * 16 + r;                        // padded row space [16384]
    int b = row >> 10, n = row & 1023;
    long po = (long)row * DN + lane;
    if (n < N_) {
      long io = ((long)b * N_ + n) * DN + lane;
      float xv = fus[io];
      float s = xv, s2 = xv * xv;
      #pragma unroll
      for (int o = 32; o > 0; o >>= 1) { s += __shfl_xor(s, o); s2 += __shfl_xor(s2, o); }
      float mean = s * (1.f / DN);
      float var  = s2 * (1.f / DN) - mean * mean;
      float fv = (xv - mean) * rsqrtf(var + 1e-5f);
      float rs = fv;
      #pragma unroll
      for (int o = 32; o > 0; o >>= 1) rs += __shfl_xor(rs, o);
      fbf[po]  = f2bf(fv);
      nv11[po] = f2bf(rs * node_w[(long)n * DN + lane] + fv);
      float xi = node_input[io];
      float q2 = xi * xi;
      #pragma unroll
      for (int o = 32; o > 0; o >>= 1) q2 += __shfl_xor(q2, o);
      if (lane == 0) sq[(long)b * N_ + n] = q2;
    } else {
      fbf[po] = 0; nv11[po] = 0;
    }
  }
}

// ---------------- batched bf16 MFMA GEMM: C[b] = X[b] · Y[b]^T (m97-style 128^2 tile) ----------------
#define GLOAD_LDS16(gp, lp) \
  __builtin_amdgcn_global_load_lds((const __attribute__((address_space(1))) void*)(gp), \
                                   (__attribute__((address_space(3))) void*)(lp), 16, 0, 0)

// EPI 1: relu -> bf16 full-tile store, stride 1024.
// EPI 2: q/k epilogue -> leaky_relu; q cols (<128) scaled by weff*0.25; bf16, row stride 256.
// EPI 3: plain bf16 full-tile store, stride 1024 (padded buffers, no bounds checks).
template<int EPI>
__global__ __launch_bounds__(256, 2)
void gemm_bt(const unsigned short* __restrict__ X, long xbs, int ldx,
             const unsigned short* __restrict__ Y, long ybs, int ldy,
             int K,
             unsigned short* __restrict__ outB, long obsB,
             const float* __restrict__ weff) {
  __shared__ __align__(16) short As[128 * 32];
  __shared__ __align__(16) short Bs[128 * 32];
  const int tid = threadIdx.x;
  const int b  = blockIdx.z;
  const int m0 = blockIdx.x * 128;
  const int n0 = blockIdx.y * 128;
  const unsigned short* Xb = X + (long)b * xbs + (long)m0 * ldx;
  const unsigned short* Yb = Y + (long)b * ybs + (long)n0 * ldy;

  const int lane = tid & 63, w = tid >> 6;
  const int wm = (w >> 1) * 64, wn = (w & 1) * 64;   // 2x2 waves -> 64x64 each
  const int fr = lane & 15, kg = lane >> 4;

  // staging map: thread -> (row sr, k-slot ks); source column XOR-swizzled so that
  // LDS[row][slot] = X[row][(slot ^ p_row)*8 ..], p_row = (row>>1)&3  (rule 21: same involution on read)
  const int sr = tid >> 2;
  const int ks = tid & 3;
  const int c1 = ((ks ^ ((sr >> 1) & 3)) * 8);
  const int c2 = ((ks ^ (((sr + 64) >> 1) & 3)) * 8);

  f32x4 acc[4][4];
  #pragma unroll
  for (int mi = 0; mi < 4; ++mi)
    #pragma unroll
    for (int ni = 0; ni < 4; ++ni)
      acc[mi][ni] = (f32x4){0.f, 0.f, 0.f, 0.f};

  const short* Asp = (const short*)As;
  const short* Bsp = (const short*)Bs;

  for (int k0 = 0; k0 < K; k0 += 32) {
    GLOAD_LDS16(Xb + (long)sr * ldx + k0 + c1,        (char*)As + tid * 16);
    GLOAD_LDS16(Xb + (long)(sr + 64) * ldx + k0 + c2, (char*)As + 4096 + tid * 16);
    GLOAD_LDS16(Yb + (long)sr * ldy + k0 + c1,        (char*)Bs + tid * 16);
    GLOAD_LDS16(Yb + (long)(sr + 64) * ldy + k0 + c2, (char*)Bs + 4096 + tid * 16);
    __syncthreads();   // compiler emits s_waitcnt vmcnt(0) before s_barrier -> LDS valid
    short8 av[4], bv[4];
    #pragma unroll
    for (int mi = 0; mi < 4; ++mi) {
      int r = wm + mi * 16 + fr;
      av[mi] = *(const short8*)&Asp[r * 32 + ((kg ^ ((r >> 1) & 3)) * 8)];
    }
    #pragma unroll
    for (int ni = 0; ni < 4; ++ni) {
      int r = wn + ni * 16 + fr;
      bv[ni] = *(const short8*)&Bsp[r * 32 + ((kg ^ ((r >> 1) & 3)) * 8)];
    }
    #pragma unroll
    for (int mi = 0; mi < 4; ++mi)
      #pragma unroll
      for (int ni = 0; ni < 4; ++ni)
        acc[mi][ni] = __builtin_amdgcn_mfma_f32_16x16x32_bf16(av[mi], bv[ni], acc[mi][ni], 0, 0, 0);
    __syncthreads();   // protect LDS from next-iter staging
  }

  // C/D layout (m89-verified): col = lane&15, row = (lane>>4)*4 + reg
  if (EPI == 1) {
    unsigned short* ob = outB + (long)b * obsB;
    #pragma unroll
    for (int mi = 0; mi < 4; ++mi) {
      #pragma unroll
      for (int ni = 0; ni < 4; ++ni) {
        int col  = n0 + wn + ni * 16 + fr;
        int rowb = m0 + wm + mi * 16 + kg * 4;
        #pragma unroll
        for (int j = 0; j < 4; ++j)
          ob[(long)(rowb + j) * NP + col] = f2bf(fmaxf(acc[mi][ni][j], 0.f));
      }
    }
  } else if (EPI == 2) {
    unsigned short* ob = outB;           // qk [16384][256]
    #pragma unroll
    for (int mi = 0; mi < 4; ++mi) {
      #pragma unroll
      for (int ni = 0; ni < 4; ++ni) {
        int col  = n0 + wn + ni * 16 + fr;      // 0..255
        int rowb = m0 + wm + mi * 16 + kg * 4;
        float sc = (col < 128) ? weff[col >> 4] * 0.25f : 1.f;
        #pragma unroll
        for (int j = 0; j < 4; ++j) {
          float v = acc[mi][ni][j];
          v = (v > 0.f) ? v : 0.01f * v;        // leaky_relu
          ob[(long)(rowb + j) * 256 + col] = f2bf(v * sc);
        }
      }
    }
  } else {
    unsigned short* ob = outB + (long)b * obsB;
    #pragma unroll
    for (int mi = 0; mi < 4; ++mi) {
      #pragma unroll
      for (int ni = 0; ni < 4; ++ni) {
        int col  = n0 + wn + ni * 16 + fr;
        int rowb = m0 + wm + mi * 16 + kg * 4;
        #pragma unroll
        for (int j = 0; j < 4; ++j)
          ob[(long)(rowb + j) * NP + col] = f2bf(acc[mi][ni][j]);
      }
    }
  }
}

// ---------------- row_combine1 (wave-per-row): t = ln(ln(apre)+ln(skip)); stat = {mean, sd} ----------------
__global__ __launch_bounds__(256)
void row_combine1(const unsigned short* __restrict__ apre, const unsigned short* __restrict__ skip,
                  unsigned short* __restrict__ tbf, float2* __restrict__ stat) {
  int w = threadIdx.x >> 6, lane = threadIdx.x & 63;
  int n = blockIdx.x * 4 + w, b = blockIdx.y;
  long base = ((long)b * NP + n) * NP;
  ushort8v a8[2], s8[2];
  #pragma unroll
  for (int c = 0; c < 2; ++c) {
    a8[c] = *(const ushort8v*)(apre + base + c * 512 + lane * 8);
    s8[c] = *(const ushort8v*)(skip + base + c * 512 + lane * 8);
  }
  float xa[16], xs[16];
  float sa = 0.f, sa2 = 0.f, ss = 0.f, ss2 = 0.f;
  #pragma unroll
  for (int c = 0; c < 2; ++c)
    #pragma unroll
    for (int j = 0; j < 8; ++j) {
      bool mm = (c * 512 + lane * 8 + j) < N_;
      float va = mm ? bf2f(a8[c][j]) : 0.f;
      float vs = mm ? bf2f(s8[c][j]) : 0.f;
      xa[c*8+j] = va; xs[c*8+j] = vs;
      sa += va; sa2 += va * va; ss += vs; ss2 += vs * vs;
    }
  sa = wred(sa); sa2 = wred(sa2); ss = wred(ss); ss2 = wred(ss2);
  float ma = sa * 1e-3f, ra = rsqrtf(sa2 * 1e-3f - ma * ma + 1e-5f);
  float ms = ss * 1e-3f, rs = rsqrtf(ss2 * 1e-3f - ms * ms + 1e-5f);
  float y[16]; float sy = 0.f, sy2 = 0.f;
  #pragma unroll
  for (int c = 0; c < 2; ++c)
    #pragma unroll
    for (int j = 0; j < 8; ++j) {
      bool mm = (c * 512 + lane * 8 + j) < N_;
      y[c*8+j] = mm ? (xa[c*8+j] - ma) * ra + (xs[c*8+j] - ms) * rs : 0.f;
      sy += y[c*8+j]; sy2 += y[c*8+j] * y[c*8+j];
    }
  sy = wred(sy); sy2 = wred(sy2);
  float my = sy * 1e-3f, vy = sy2 * 1e-3f - my * my;
  float ry = rsqrtf(vy + 1e-5f);
  #pragma unroll
  for (int c = 0; c < 2; ++c) {
    ushort8v o;
    #pragma unroll
    for (int j = 0; j < 8; ++j) {
      bool mm = (c * 512 + lane * 8 + j) < N_;
      o[j] = mm ? f2bf((y[c*8+j] - my) * ry) : (unsigned short)0;
    }
    *(ushort8v*)(tbf + base + c * 512 + lane * 8) = o;
  }
  if (lane == 0) stat[(long)b * NP + n] = make_float2(my, sqrtf(vy + 1e-5f));
}

// ---------------- row_final (wave-per-row): ln(G2 + (t*sd+my)); +sgi; ln; relu; softmax ----------------
__global__ __launch_bounds__(256)
void row_final(const unsigned short* __restrict__ g2, const unsigned short* __restrict__ tbf,
               const float2* __restrict__ stat, const float* __restrict__ sgi,
               float* __restrict__ outp) {
  int w = threadIdx.x >> 6, lane = threadIdx.x & 63;
  int n = blockIdx.x * 4 + w, b = blockIdx.y;
  long base = ((long)b * NP + n) * NP;
  float2 st = stat[(long)b * NP + n];   // {mean, sd} of adj_bf's inner ln
  ushort8v g8[2], t8[2];
  float gr[16];
  #pragma unroll
  for (int c = 0; c < 2; ++c) {
    g8[c] = *(const ushort8v*)(g2  + base + c * 512 + lane * 8);
    t8[c] = *(const ushort8v*)(tbf + base + c * 512 + lane * 8);
    float4 v0 = *(const float4*)(sgi + (long)n * NP + c * 512 + lane * 8);
    float4 v1 = *(const float4*)(sgi + (long)n * NP + c * 512 + lane * 8 + 4);
    gr[c*8+0]=v0.x; gr[c*8+1]=v0.y; gr[c*8+2]=v0.z; gr[c*8+3]=v0.w;
    gr[c*8+4]=v1.x; gr[c*8+5]=v1.y; gr[c*8+6]=v1.z; gr[c*8+7]=v1.w;
  }
  float x[16]; float s = 0.f, s2 = 0.f;
  #pragma unroll
  for (int c = 0; c < 2; ++c)
    #pragma unroll
    for (int j = 0; j < 8; ++j) {
      bool mm = (c * 512 + lane * 8 + j) < N_;
      x[c*8+j] = mm ? bf2f(g8[c][j]) + (bf2f(t8[c][j]) * st.y + st.x) : 0.f;
      s += x[c*8+j]; s2 += x[c*8+j] * x[c*8+j];
    }
  s = wred(s); s2 = wred(s2);
  float m1 = s * 1e-3f, r1 = rsqrtf(s2 * 1e-3f - m1 * m1 + 1e-5f);
  s = 0.f; s2 = 0.f;
  #pragma unroll
  for (int c = 0; c < 2; ++c)
    #pragma unroll
    for (int j = 0; j < 8; ++j) {
      bool mm = (c * 512 + lane * 8 + j) < N_;
      x[c*8+j] = mm ? (x[c*8+j] - m1) * r1 + gr[c*8+j] : 0.f;
      s += x[c*8+j]; s2 += x[c*8+j] * x[c*8+j];
    }
  s = wred(s); s2 = wred(s2);
  float m2 = s * 1e-3f, r2 = rsqrtf(s2 * 1e-3f - m2 * m2 + 1e-5f);
  float mx = -1e30f;
  #pragma unroll
  for (int c = 0; c < 2; ++c)
    #pragma unroll
    for (int j = 0; j < 8; ++j) {
      if ((c * 512 + lane * 8 + j) < N_) {
        x[c*8+j] = fmaxf((x[c*8+j] - m2) * r2, 0.f); mx = fmaxf(mx, x[c*8+j]);
      }
    }
  mx = wredmax(mx);
  float es = 0.f;
  #pragma unroll
  for (int c = 0; c < 2; ++c)
    #pragma unroll
    for (int j = 0; j < 8; ++j) {
      if ((c * 512 + lane * 8 + j) < N_) { x[c*8+j] = __expf(x[c*8+j] - mx); es += x[c*8+j]; }
      else x[c*8+j] = 0.f;
    }
  es = wred(es);
  float inv = 1.f / es;
  float* orow = outp + (long)b * 1000000 + (long)n * N_;
  #pragma unroll
  for (int c = 0; c < 2; ++c) {
    int bse = c * 512 + lane * 8;
    if (bse < N_) {                       // 1000 % 8 == 0 -> full-chunk masking valid
      float4 o0 = make_float4(x[c*8+0]*inv, x[c*8+1]*inv, x[c*8+2]*inv, x[c*8+3]*inv);
      float4 o1 = make_float4(x[c*8+4]*inv, x[c*8+5]*inv, x[c*8+6]*inv, x[c*8+7]*inv);
      *(float4*)(orow + bse) = o0;
      *(float4*)(orow + bse + 4) = o1;
    }
  }
}

// ---------------- adj_static broadcast to [B,N,N] ----------------
__global__ void broadcast_static(const float* __restrict__ adjs, float* __restrict__ out1) {
  long i = (long)blockIdx.x * 256 + threadIdx.x;   // over 250,000 float4
  if (i < 250000) {
    float4 v = ((const float4*)adjs)[i];
    #pragma unroll
    for (int b = 0; b < B_; ++b) ((float4*)out1)[(long)b * 250000 + i] = v;
  }
}

__global__ void copy_s(const float* __restrict__ src, float* __restrict__ dst) {
  int i = blockIdx.x * 256 + threadIdx.x;
  if (i < N_ * DN) dst[i] = src[i];
}

// ---------------- colsum + Frobenius of adj_static (segmented, atomic-accumulated) ----------------
__global__ void colsum_fnorm(const float* __restrict__ adjs, float* __restrict__ colsum,
                             float* __restrict__ fnorm) {
  int m = blockIdx.x * 256 + threadIdx.x;      // 0..1023
  int n0 = blockIdx.y * 63;                    // 16 segments x 63 rows >= 1000
  int ne = min(n0 + 63, N_);
  float c = 0.f, f = 0.f;
  if (m < N_) {
    for (int n = n0; n < ne; ++n) { float v = adjs[(long)n * N_ + m]; c += v; f += v * v; }
    atomicAdd(&colsum[m], c);
  }
  float d = 0.f; block_red2(f, d);
  if (threadIdx.x == 0) atomicAdd(fnorm, f);
}

// ---------------- trace term: tr[b] += sum_{m,d} (A^T X_b)[m,d] * X_b[m,d]  ----------------
__global__ __launch_bounds__(256)
void trace_kernel(const float* __restrict__ adjs, const float* __restrict__ x,
                  float* __restrict__ tr) {
  __shared__ float A_s[64 * 64];
  __shared__ float X_s[64 * 64];
  const int tid = threadIdx.x;
  const int tx = tid & 15, ty = tid >> 4;
  const int m0 = blockIdx.x * 64;
  const int b  = blockIdx.y;
  const int nseg = blockIdx.z;
  const float* xb = x + (long)b * (N_ * DN);

  float acc[4][4];
  #pragma unroll
  for (int i = 0; i < 4; ++i)
    #pragma unroll
    for (int j = 0; j < 4; ++j) acc[i][j] = 0.f;

  for (int cc = 0; cc < 4; ++cc) {
    int n0 = (nseg * 4 + cc) * 64;
    #pragma unroll
    for (int k = 0; k < 16; ++k) {
      int i = tid + k * 256;                 // 0..4095
      int nn = i >> 6, cm = i & 63;
      int n = n0 + nn;
      A_s[i] = (n < N_ && (m0 + cm) < N_) ? adjs[(long)n * N_ + m0 + cm] : 0.f;
      X_s[i] = (n < N_) ? xb[(long)n * DN + cm] : 0.f;
    }
    __syncthreads();
    #pragma unroll 8
    for (int nn = 0; nn < 64; ++nn) {
      float4 av = *(const float4*)&A_s[nn * 64 + ty * 4];   // m-direction
      float4 xv = *(const float4*)&X_s[nn * 64 + tx * 4];   // d-direction
      #pragma unroll
      for (int i = 0; i < 4; ++i) {
        float a = (&av.x)[i];
        acc[i][0] += a * xv.x;
        acc[i][1] += a * xv.y;
        acc[i][2] += a * xv.z;
        acc[i][3] += a * xv.w;
      }
    }
    __syncthreads();
  }

  float v = 0.f;
  #pragma unroll
  for (int i = 0; i < 4; ++i) {
    int m = m0 + ty * 4 + i;
    if (m < N_) {
      float4 xm = *(const float4*)&xb[(long)m * DN + tx * 4];
      v += acc[i][0] * xm.x + acc[i][1] * xm.y + acc[i][2] * xm.z + acc[i][3] * xm.w;
    }
  }
  float d = 0.f; block_red2(v, d);
  if (tid == 0) atomicAdd(&tr[b], v);
}

// ---------------- gl_loss ----------------
__global__ void gl_final(const float* __restrict__ sq, const float* __restrict__ rowsum,
                         const float* __restrict__ colsum, const float* __restrict__ tr,
                         const float* __restrict__ fnorm, float* __restrict__ gl) {
  int b = blockIdx.x, tid = threadIdx.x;
  float s = 0.f;
  for (int i = tid; i < N_; i += 256) s += sq[(long)b * N_ + i] * (rowsum[i] + colsum[i]);
  float d = 0.f; block_red2(s, d);
  if (tid == 0) gl[b] = (s - 2.f * tr[b]) * 1e-3f + fnorm[0] * 1e-3f;
}

// ---------------- launch ----------------
extern "C" void kernel_launch(void* const* d_in, const int* in_sizes, int n_in,
                              void* d_out, int out_size, void* d_ws, size_t ws_size,
                              hipStream_t stream) {
  (void)in_sizes; (void)n_in; (void)out_size; (void)ws_size;
  const float* nodevec_fusion = (const float*)d_in[0];
  const float* nodevec_s      = (const float*)d_in[1];
  const float* node_input     = (const float*)d_in[2];
  const float* nodevec_dy     = (const float*)d_in[3];
  const float* w_q            = (const float*)d_in[4];
  const float* w_k            = (const float*)d_in[5];
  const float* node_w         = (const float*)d_in[6];
  const float* mlp_w          = (const float*)d_in[7];
  const float* mlp_b          = (const float*)d_in[8];
  const float* attn_linear    = (const float*)d_in[9];
  const float* attn_linear_1  = (const float*)d_in[10];

  float* out  = (float*)d_out;
  float* out0 = out;               // adj_dynamic [16,1000,1000]
  float* out1 = out + 16000000;    // adj_static_b
  float* outS = out + 32000000;    // nodevec_s copy
  float* outGL = out + 32064000;   // gl_loss[16]

  char* wp = (char*)d_ws;
  auto alloc = [&](size_t bytes) { char* p = wp; wp += (bytes + 255) & ~(size_t)255; return p; };
  float* adjs            = (float*)alloc((size_t)N_ * N_ * 4);
  float* sgi             = (float*)alloc((size_t)NP * NP * 4);            // stride 1024
  unsigned short* apre   = (unsigned short*)alloc((size_t)B_ * NP * NP * 2);  // A_pre, reused as G2
  unsigned short* skipb  = (unsigned short*)alloc((size_t)B_ * NP * NP * 2);  // skip_pre
  unsigned short* tbf    = (unsigned short*)alloc((size_t)B_ * NP * NP * 2);
  unsigned short* afbf   = (unsigned short*)alloc((size_t)B_ * NP * NP * 2);
  unsigned short* L1T    = (unsigned short*)alloc((size_t)NP * NP * 2);
  unsigned short* L2T    = (unsigned short*)alloc((size_t)NP * NP * 2);
  unsigned short* nv11   = (unsigned short*)alloc((size_t)B_ * NP * DN * 2);
  unsigned short* fbf    = (unsigned short*)alloc((size_t)B_ * NP * DN * 2);
  unsigned short* qk     = (unsigned short*)alloc((size_t)B_ * NP * 256 * 2);
  unsigned short* wt     = (unsigned short*)alloc((size_t)256 * DN * 2);
  float2* stat           = (float2*)alloc((size_t)B_ * NP * 8);
  float* sq              = (float*)alloc((size_t)B_ * N_ * 4);
  float* colsum          = (float*)alloc(4096);
  float* rowsum          = (float*)alloc(4096);
  float* weff            = (float*)alloc(256);
  float* tr              = (float*)alloc(256);
  float* fnorm           = (float*)alloc(256);

  prep_kernel<<<1, 1024, 0, stream>>>(mlp_w, mlp_b, w_q, w_k, weff, tr, fnorm, colsum, wt);
  transpose_pad<<<dim3(32, 32), dim3(32, 8), 0, stream>>>(attn_linear,   L1T);
  transpose_pad<<<dim3(32, 32), dim3(32, 8), 0, stream>>>(attn_linear_1, L2T);
  gram_kernel<<<dim3(16, 16), 256, 0, stream>>>(nodevec_s,  adjs, N_);
  gram_kernel<<<dim3(16, 16), 256, 0, stream>>>(nodevec_dy, sgi, NP);
  row_ln_sm<<<250, 256, 0, stream>>>(adjs, rowsum);                        // adj_static
  row_ln<<<250, 256, 0, stream>>>(sgi, NP);                                // static_graph_inf
  fusion_ln<<<256, 256, 0, stream>>>(nodevec_fusion, node_w, node_input, fbf, nv11, sq);
  // qk = leaky(f @ [w_q|w_k]) with weff*0.25 folded into q cols
  gemm_bt<2><<<dim3(128, 2, 1), 256, 0, stream>>>(fbf, 0L, DN,
                                                  wt, 0L, DN, DN,
                                                  qk, 0L, weff);
  // skip_pre = nv11 · nv11^T -> bf16
  gemm_bt<3><<<dim3(8, 8, 16), 256, 0, stream>>>(nv11, (long)NP * DN, DN,
                                                 nv11, (long)NP * DN, DN, DN,
                                                 skipb, (long)NP * NP, (const float*)nullptr);
  // A_pre = q · k^T -> bf16   (q = qk cols 0..127, k = qk cols 128..255)
  gemm_bt<3><<<dim3(8, 8, 16), 256, 0, stream>>>(qk, (long)NP * 256, 256,
                                                 qk + 128, (long)NP * 256, 256, D_,
                                                 apre, (long)NP * NP, (const float*)nullptr);
  // t = ln(ln(A_pre) + ln(skip_pre)); stat = {mean, sd} of the outer ln
  row_combine1<<<dim3(250, 16), 256, 0, stream>>>(apre, skipb, tbf, stat);
  // adj_af = relu(t @ L1) -> bf16
  gemm_bt<1><<<dim3(8, 8, 16), 256, 0, stream>>>(tbf, (long)NP * NP, NP,
                                                 L1T, 0L, NP, NP,
                                                 afbf, (long)NP * NP, (const float*)nullptr);
  // G2 = adj_af @ L2 -> bf16 (reuse apre buffer)
  gemm_bt<3><<<dim3(8, 8, 16), 256, 0, stream>>>(afbf, (long)NP * NP, NP,
                                                 L2T, 0L, NP, NP,
                                                 apre, (long)NP * NP, (const float*)nullptr);
  row_final<<<dim3(250, 16), 256, 0, stream>>>(apre, tbf, stat, sgi, out0);  // adj_dynamic
  broadcast_static<<<977, 256, 0, stream>>>(adjs, out1);                   // adj_static_b
  copy_s<<<250, 256, 0, stream>>>(nodevec_s, outS);
  colsum_fnorm<<<dim3(4, 16), 256, 0, stream>>>(adjs, colsum, fnorm);
  trace_kernel<<<dim3(16, 16, 4), 256, 0, stream>>>(adjs, node_input, tr);
  gl_final<<<16, 256, 0, stream>>>(sq, rowsum, colsum, tr, fnorm, outGL);
}